// Round 1
// baseline (311.052 us; speedup 1.0000x reference)
//
#include <hip/hip_runtime.h>

typedef unsigned short u16;
typedef unsigned int   u32;
typedef __bf16 bf16_t;
typedef bf16_t bf16x8 __attribute__((ext_vector_type(8)));
typedef float  f32x4  __attribute__((ext_vector_type(4)));

#define E_DIM 1024
#define T_DIM 2048
#define H_NUM 16
#define DH 64
#define BT 4096          // B*T
#define Y_LD 3072        // QKV fused row stride

__device__ __forceinline__ u16 f2bf(float f) {
  u32 u = __builtin_bit_cast(u32, f);
  u32 r = (u + 0x7fffu + ((u >> 16) & 1u)) >> 16;
  return (u16)r;
}

// XOR swizzle for [R][64]-element bf16 LDS tiles (row = 128B): spreads the
// 16-lane stride-128B ds_read_b128 pattern across 8 bank slots (G4 / T2).
__device__ __forceinline__ int swz(int r, int c) {
  return r * 64 + (c ^ ((r & 7) << 3));
}

__device__ __forceinline__ void store_val(float* p, float v) { *p = v; }
__device__ __forceinline__ void store_val(u16* p, float v)   { *p = f2bf(v); }

// ---------------- prep kernels ----------------
__global__ void k_cast_bf16(const float* __restrict__ in, u16* __restrict__ out, int n) {
  int i = (blockIdx.x * blockDim.x + threadIdx.x) * 4;
  if (i + 3 < n) {
    float4 v = *reinterpret_cast<const float4*>(in + i);
    u32 lo = (u32)f2bf(v.x) | ((u32)f2bf(v.y) << 16);
    u32 hi = (u32)f2bf(v.z) | ((u32)f2bf(v.w) << 16);
    *reinterpret_cast<uint2*>(out + i) = make_uint2(lo, hi);
  }
}

// Weff[o][i] = W[o][i] + 2 * sum_r A[o][r] * Bm[r][i]   (rank-8 LoRA fold)
__global__ void k_weff(const float* __restrict__ W, const float* __restrict__ A,
                       const float* __restrict__ Bm, u16* __restrict__ out) {
  int idx = blockIdx.x * blockDim.x + threadIdx.x;
  int o = idx >> 10, i = idx & 1023;
  float acc = W[idx];
#pragma unroll
  for (int r = 0; r < 8; ++r) acc += 2.0f * A[o * 8 + r] * Bm[r * 1024 + i];
  out[idx] = f2bf(acc);
}

// ---------------- GEMM: C[m][n] = sum_k A[m][k] * B[n][k] ----------------
// A [M][K] bf16, B [N][K] bf16 (both K-contiguous), 128x128 tile, BK=64.
template <typename OUT_T>
__global__ __launch_bounds__(256) void k_gemm_bt(
    const u16* __restrict__ A, const u16* __restrict__ B,
    OUT_T* __restrict__ C, int K, int ldc) {
  __shared__ __align__(16) u16 As[128 * 64];
  __shared__ __align__(16) u16 Bs[128 * 64];
  const int tid  = threadIdx.x;
  const int lane = tid & 63;
  const int wave = tid >> 6;
  const int wr = wave >> 1, wc = wave & 1;
  const int m0 = blockIdx.y * 128;
  const int n0 = blockIdx.x * 128;
  const int lr = lane & 15;
  const int lk = (lane >> 4) * 8;

  f32x4 acc[4][4] = {};

  for (int k0 = 0; k0 < K; k0 += 64) {
    __syncthreads();
#pragma unroll
    for (int p = 0; p < 4; ++p) {
      int e = p * 2048 + tid * 8;
      int r = e >> 6, c = e & 63;
      uint4 va = *reinterpret_cast<const uint4*>(&A[(size_t)(m0 + r) * K + k0 + c]);
      uint4 vb = *reinterpret_cast<const uint4*>(&B[(size_t)(n0 + r) * K + k0 + c]);
      *reinterpret_cast<uint4*>(&As[swz(r, c)]) = va;
      *reinterpret_cast<uint4*>(&Bs[swz(r, c)]) = vb;
    }
    __syncthreads();
#pragma unroll
    for (int kk = 0; kk < 2; ++kk) {
      bf16x8 af[4], bfr[4];
#pragma unroll
      for (int mi = 0; mi < 4; ++mi)
        af[mi] = *reinterpret_cast<const bf16x8*>(&As[swz(wr * 64 + mi * 16 + lr, kk * 32 + lk)]);
#pragma unroll
      for (int ni = 0; ni < 4; ++ni)
        bfr[ni] = *reinterpret_cast<const bf16x8*>(&Bs[swz(wc * 64 + ni * 16 + lr, kk * 32 + lk)]);
#pragma unroll
      for (int mi = 0; mi < 4; ++mi)
#pragma unroll
        for (int ni = 0; ni < 4; ++ni)
          acc[mi][ni] = __builtin_amdgcn_mfma_f32_16x16x32_bf16(af[mi], bfr[ni], acc[mi][ni], 0, 0, 0);
    }
  }
  const int rg = (lane >> 4) * 4;
#pragma unroll
  for (int mi = 0; mi < 4; ++mi)
#pragma unroll
    for (int ni = 0; ni < 4; ++ni)
#pragma unroll
      for (int q = 0; q < 4; ++q) {
        int row = m0 + wr * 64 + mi * 16 + rg + q;
        int col = n0 + wc * 64 + ni * 16 + lr;
        store_val(&C[(size_t)row * ldc + col], acc[mi][ni][q]);
      }
}

// ---------------- flash attention with ALiBi + causal ----------------
// Y: [BT][3072] fused Q|K|V bf16.  Og: [BT][1024] bf16 output (pre-proj).
// grid: (T/64, B*H); block 256 (4 waves); wave w owns q rows [q0+w*16, +16).
__global__ __launch_bounds__(256) void k_attn(
    const u16* __restrict__ Y, u16* __restrict__ Og) {
  __shared__ __align__(16) u16 Vt[64 * 64];       // V transposed [d][k], swizzled
  __shared__ __align__(16) u16 Pl[4 * 16 * 64];   // per-wave P tiles, swizzled

  const int tid  = threadIdx.x;
  const int lane = tid & 63;
  const int wave = tid >> 6;
  const int qt = blockIdx.x;
  const int bh = blockIdx.y;
  const int b = bh >> 4, h = bh & 15;
  const int lr = lane & 15;
  const int lg = lane >> 4;
  const int lk = lg * 8;
  const int q0 = qt * 64;

  const float slope = exp2f(-0.5f * (float)(h + 1));
  const float isq = 0.125f;  // 1/sqrt(64)

  const u16* Kp = Y + 1024;
  const u16* Vp = Y + 2048;

  // Q fragments, held in registers for the whole block
  const int qrow = q0 + wave * 16 + lr;
  bf16x8 qf[2];
#pragma unroll
  for (int kk = 0; kk < 2; ++kk)
    qf[kk] = *reinterpret_cast<const bf16x8*>(
        &Y[(size_t)(b * T_DIM + qrow) * Y_LD + h * DH + kk * 32 + lk]);

  f32x4 oacc[4] = {};
  float mrow[4], lrow[4];
#pragma unroll
  for (int r = 0; r < 4; ++r) { mrow[r] = -INFINITY; lrow[r] = 0.f; }

  u16* Plw = Pl + wave * 16 * 64;

  for (int kt = 0; kt <= qt; ++kt) {
    const int kv0 = kt * 64;
    __syncthreads();  // prev PV reads of Vt done before restaging
    // stage V transposed: Vt[d][k]
#pragma unroll
    for (int p = 0; p < 2; ++p) {
      int cid = p * 256 + tid;
      int kr = cid >> 3, dc = (cid & 7) * 8;
      uint4 v = *reinterpret_cast<const uint4*>(
          &Vp[(size_t)(b * T_DIM + kv0 + kr) * Y_LD + h * DH + dc]);
      const u16* e = reinterpret_cast<const u16*>(&v);
#pragma unroll
      for (int j = 0; j < 8; ++j) Vt[swz(dc + j, kr)] = e[j];
    }
    // S = Q K^T (K fragments straight from global; L1/L2-resident)
    f32x4 sacc[4] = {};
#pragma unroll
    for (int kk = 0; kk < 2; ++kk)
#pragma unroll
      for (int ni = 0; ni < 4; ++ni) {
        bf16x8 kf = *reinterpret_cast<const bf16x8*>(
            &Kp[(size_t)(b * T_DIM + kv0 + ni * 16 + lr) * Y_LD + h * DH + kk * 32 + lk]);
        sacc[ni] = __builtin_amdgcn_mfma_f32_16x16x32_bf16(qf[kk], kf, sacc[ni], 0, 0, 0);
      }
    // epilogue: scale + alibi + causal mask, online softmax
    float svals[4][4], rmax[4], rsum[4], alpha[4];
#pragma unroll
    for (int r = 0; r < 4; ++r) rmax[r] = -INFINITY;
#pragma unroll
    for (int ni = 0; ni < 4; ++ni) {
      int kg = kv0 + ni * 16 + lr;
#pragma unroll
      for (int r = 0; r < 4; ++r) {
        int qg = q0 + wave * 16 + lg * 4 + r;
        float s = sacc[ni][r] * isq + slope * (float)(qg - kg);
        if (kg > qg) s = -INFINITY;
        svals[ni][r] = s;
        rmax[r] = fmaxf(rmax[r], s);
      }
    }
#pragma unroll
    for (int r = 0; r < 4; ++r) {
#pragma unroll
      for (int off = 1; off < 16; off <<= 1)
        rmax[r] = fmaxf(rmax[r], __shfl_xor(rmax[r], off));
      float mn = fmaxf(mrow[r], rmax[r]);
      alpha[r] = __expf(mrow[r] - mn);   // first tile: exp(-inf)=0
      mrow[r] = mn;
      rsum[r] = 0.f;
    }
#pragma unroll
    for (int ni = 0; ni < 4; ++ni)
#pragma unroll
      for (int r = 0; r < 4; ++r) {
        float pv = __expf(svals[ni][r] - mrow[r]);  // masked -> 0
        rsum[r] += pv;
        Plw[swz(lg * 4 + r, ni * 16 + lr)] = f2bf(pv);
      }
#pragma unroll
    for (int r = 0; r < 4; ++r) {
#pragma unroll
      for (int off = 1; off < 16; off <<= 1)
        rsum[r] += __shfl_xor(rsum[r], off);
      lrow[r] = lrow[r] * alpha[r] + rsum[r];
#pragma unroll
      for (int f = 0; f < 4; ++f) oacc[f][r] *= alpha[r];
    }
    __syncthreads();  // Vt staged + P visible (P is same-wave, barrier covers Vt)
    // O += P @ V
#pragma unroll
    for (int kk = 0; kk < 2; ++kk) {
      bf16x8 pf = *reinterpret_cast<const bf16x8*>(&Plw[swz(lr, kk * 32 + lk)]);
#pragma unroll
      for (int f = 0; f < 4; ++f) {
        bf16x8 vf = *reinterpret_cast<const bf16x8*>(&Vt[swz(f * 16 + lr, kk * 32 + lk)]);
        oacc[f] = __builtin_amdgcn_mfma_f32_16x16x32_bf16(pf, vf, oacc[f], 0, 0, 0);
      }
    }
  }
  // normalize + store
#pragma unroll
  for (int f = 0; f < 4; ++f)
#pragma unroll
    for (int r = 0; r < 4; ++r) {
      int q = q0 + wave * 16 + lg * 4 + r;
      float v = oacc[f][r] / lrow[r];
      Og[(size_t)(b * T_DIM + q) * E_DIM + h * DH + f * 16 + lr] = f2bf(v);
    }
}

extern "C" void kernel_launch(void* const* d_in, const int* in_sizes, int n_in,
                              void* d_out, int out_size, void* d_ws, size_t ws_size,
                              hipStream_t stream) {
  const float* x  = (const float*)d_in[0];
  const float* Wq = (const float*)d_in[1];
  const float* Aq = (const float*)d_in[2];
  const float* Bq = (const float*)d_in[3];
  const float* Wk = (const float*)d_in[4];
  const float* Ak = (const float*)d_in[5];
  const float* Bk = (const float*)d_in[6];
  const float* Wv = (const float*)d_in[7];
  const float* Av = (const float*)d_in[8];
  const float* Bv = (const float*)d_in[9];
  const float* Wp = (const float*)d_in[10];
  float* out = (float*)d_out;

  char* ws = (char*)d_ws;
  u16* xb   = (u16*)(ws);                        // 4096x1024 bf16  (8 MB)
  u16* Weff = (u16*)(ws + 8388608);              // 3x1024x1024 bf16 (6 MB)
  u16* Wpb  = (u16*)(ws + 14680064);             // 1024x1024 bf16  (2 MB)
  u16* Yq   = (u16*)(ws + 16777216);             // 4096x3072 bf16  (24 MB)
  u16* Og   = (u16*)(ws + 41943040);             // 4096x1024 bf16  (8 MB)

  // 1) cast x to bf16
  k_cast_bf16<<<4096, 256, 0, stream>>>(x, xb, BT * E_DIM);
  // 2) fold LoRA: Weff = W + 2*A@B  (q,k,v stacked)
  k_weff<<<4096, 256, 0, stream>>>(Wq, Aq, Bq, Weff);
  k_weff<<<4096, 256, 0, stream>>>(Wk, Ak, Bk, Weff + 1024 * 1024);
  k_weff<<<4096, 256, 0, stream>>>(Wv, Av, Bv, Weff + 2 * 1024 * 1024);
  // 3) cast Wp
  k_cast_bf16<<<1024, 256, 0, stream>>>(Wp, Wpb, E_DIM * E_DIM);
  // 4) fused QKV GEMM: Y = xb @ Weff^T   [4096 x 3072]
  {
    dim3 grid(Y_LD / 128, BT / 128);
    k_gemm_bt<u16><<<grid, 256, 0, stream>>>(xb, Weff, Yq, E_DIM, Y_LD);
  }
  // 5) attention
  {
    dim3 grid(T_DIM / 64, 2 * H_NUM);
    k_attn<<<grid, 256, 0, stream>>>(Yq, Og);
  }
  // 6) output projection: out = Og @ Wp^T  (fp32 out)
  {
    dim3 grid(E_DIM / 128, BT / 128);
    k_gemm_bt<float><<<grid, 256, 0, stream>>>(Og, Wpb, out, E_DIM, E_DIM);
  }
}

// Round 2
// 256.543 us; speedup vs baseline: 1.2125x; 1.2125x over previous
//
#include <hip/hip_runtime.h>

typedef unsigned short u16;
typedef unsigned int   u32;
typedef __bf16 bf16_t;
typedef bf16_t bf16x8 __attribute__((ext_vector_type(8)));
typedef float  f32x4  __attribute__((ext_vector_type(4)));

#define E_DIM 1024
#define T_DIM 2048
#define H_NUM 16
#define DH 64
#define BT 4096          // B*T
#define Y_LD 3072        // QKV fused row stride

__device__ __forceinline__ u16 f2bf(float f) {
  u32 u = __builtin_bit_cast(u32, f);
  u32 r = (u + 0x7fffu + ((u >> 16) & 1u)) >> 16;
  return (u16)r;
}

__device__ __forceinline__ float fexp2(float x) {
#if __has_builtin(__builtin_amdgcn_exp2f)
  return __builtin_amdgcn_exp2f(x);
#else
  return exp2f(x);
#endif
}

// XOR swizzle for [R][64]-element bf16 LDS tiles (row = 128B).
__device__ __forceinline__ int swz(int r, int c) {
  return r * 64 + (c ^ ((r & 7) << 3));
}
// P-tile swizzle with 72-element row stride (bank-spread + 16B aligned).
__device__ __forceinline__ int swzp(int r, int c) {
  return r * 72 + (c ^ ((r & 7) << 3));
}

__device__ __forceinline__ void store_val(float* p, float v) { *p = v; }
__device__ __forceinline__ void store_val(u16* p, float v)   { *p = f2bf(v); }

typedef __attribute__((address_space(3))) unsigned int as3_u32;
typedef const __attribute__((address_space(1))) unsigned int as1_u32;

__device__ __forceinline__ void async16(const u16* g, u16* l) {
  __builtin_amdgcn_global_load_lds((as1_u32*)g, (as3_u32*)l, 16, 0, 0);
}

// ---------------- prep kernels ----------------
__global__ void k_cast_bf16(const float* __restrict__ in, u16* __restrict__ out, int n) {
  int i = (blockIdx.x * blockDim.x + threadIdx.x) * 4;
  if (i + 3 < n) {
    float4 v = *reinterpret_cast<const float4*>(in + i);
    u32 lo = (u32)f2bf(v.x) | ((u32)f2bf(v.y) << 16);
    u32 hi = (u32)f2bf(v.z) | ((u32)f2bf(v.w) << 16);
    *reinterpret_cast<uint2*>(out + i) = make_uint2(lo, hi);
  }
}

// Weff[o][i] = W[o][i] + 2 * sum_r A[o][r] * Bm[r][i]   (rank-8 LoRA fold)
__global__ void k_weff(const float* __restrict__ W, const float* __restrict__ A,
                       const float* __restrict__ Bm, u16* __restrict__ out) {
  int idx = blockIdx.x * blockDim.x + threadIdx.x;
  int o = idx >> 10, i = idx & 1023;
  float acc = W[idx];
#pragma unroll
  for (int r = 0; r < 8; ++r) acc += 2.0f * A[o * 8 + r] * Bm[r * 1024 + i];
  out[idx] = f2bf(acc);
}

// V transpose: Vt[b][h][d][t]  <-  Y[(b*T+t)*3072 + 2048 + h*64 + d]
__global__ __launch_bounds__(256) void k_vtrans(const u16* __restrict__ Y, u16* __restrict__ Vt) {
  __shared__ u16 tile[64 * 65];
  const int tid = threadIdx.x;
  const int bh = blockIdx.y;
  const int b = bh >> 4, h = bh & 15;
  const int t0 = blockIdx.x * 64;
  const u16* src = Y + (size_t)(b * T_DIM + t0) * Y_LD + 2048 + h * DH;
#pragma unroll
  for (int p = 0; p < 2; ++p) {
    int idx = p * 256 + tid;
    int tr = idx >> 3, dc = (idx & 7) * 8;
    uint4 v = *reinterpret_cast<const uint4*>(src + (size_t)tr * Y_LD + dc);
    const u16* e = reinterpret_cast<const u16*>(&v);
#pragma unroll
    for (int j = 0; j < 8; ++j) tile[tr * 65 + dc + j] = e[j];
  }
  __syncthreads();
  u16* dst = Vt + (size_t)bh * DH * T_DIM + t0;
#pragma unroll
  for (int p = 0; p < 2; ++p) {
    int idx = p * 256 + tid;
    int dr = idx >> 3, tc = (idx & 7) * 8;
    u16 tmp[8];
#pragma unroll
    for (int j = 0; j < 8; ++j) tmp[j] = tile[(tc + j) * 65 + dr];
    *reinterpret_cast<uint4*>(dst + (size_t)dr * T_DIM + tc) = *reinterpret_cast<const uint4*>(tmp);
  }
}

// ---------------- GEMM: C[m][n] = sum_k A[m][k] * B[n][k] ----------------
// global_load_lds staging: linear LDS dest + pre-swizzled global source (m97/m201).
template <typename OUT_T>
__global__ __launch_bounds__(256) void k_gemm_bt(
    const u16* __restrict__ A, const u16* __restrict__ B,
    OUT_T* __restrict__ C, int K, int ldc) {
  __shared__ __align__(16) u16 As[128 * 64];
  __shared__ __align__(16) u16 Bs[128 * 64];
  const int tid  = threadIdx.x;
  const int lane = tid & 63;
  const int wave = tid >> 6;
  const int wr = wave >> 1, wc = wave & 1;
  const int m0 = blockIdx.y * 128;
  const int n0 = blockIdx.x * 128;
  const int lr = lane & 15;
  const int lk = (lane >> 4) * 8;

  f32x4 acc[4][4] = {};

  for (int k0 = 0; k0 < K; k0 += 64) {
    __syncthreads();
#pragma unroll
    for (int p = 0; p < 4; ++p) {
      const int off = (p * 4 + wave) * 512;     // element offset (1KB chunks/wave)
      const int e = off + lane * 8;
      const int r = e >> 6, c = e & 63;
      const int cs = c ^ ((r & 7) << 3);        // pre-swizzled source column
      async16(&A[(size_t)(m0 + r) * K + k0 + cs], As + off);
      async16(&B[(size_t)(n0 + r) * K + k0 + cs], Bs + off);
    }
    __syncthreads();
#pragma unroll
    for (int kk = 0; kk < 2; ++kk) {
      bf16x8 af[4], bfr[4];
#pragma unroll
      for (int mi = 0; mi < 4; ++mi)
        af[mi] = *reinterpret_cast<const bf16x8*>(&As[swz(wr * 64 + mi * 16 + lr, kk * 32 + lk)]);
#pragma unroll
      for (int ni = 0; ni < 4; ++ni)
        bfr[ni] = *reinterpret_cast<const bf16x8*>(&Bs[swz(wc * 64 + ni * 16 + lr, kk * 32 + lk)]);
#pragma unroll
      for (int mi = 0; mi < 4; ++mi)
#pragma unroll
        for (int ni = 0; ni < 4; ++ni)
          acc[mi][ni] = __builtin_amdgcn_mfma_f32_16x16x32_bf16(af[mi], bfr[ni], acc[mi][ni], 0, 0, 0);
    }
  }
  const int rg = (lane >> 4) * 4;
#pragma unroll
  for (int mi = 0; mi < 4; ++mi)
#pragma unroll
    for (int ni = 0; ni < 4; ++ni)
#pragma unroll
      for (int q = 0; q < 4; ++q) {
        int row = m0 + wr * 64 + mi * 16 + rg + q;
        int col = n0 + wc * 64 + ni * 16 + lr;
        store_val(&C[(size_t)row * ldc + col], acc[mi][ni][q]);
      }
}

// ---------------- barrier-free flash attention with ALiBi + causal ----------------
// grid: 1024 blocks (XCD-chunked remap -> qt, bh); 4 independent waves/block,
// wave w owns q rows [qt*64 + w*16, +16). K from Y, V^T from Vt (global->L2).
__global__ __launch_bounds__(256) void k_attn2(
    const u16* __restrict__ Y, const u16* __restrict__ Vt, u16* __restrict__ Og) {
  __shared__ __align__(16) u16 Pl[4 * 16 * 72];

  const int tid  = threadIdx.x;
  const int lane = tid & 63;
  const int wave = tid >> 6;
  const int lr = lane & 15;
  const int lg = lane >> 4;
  const int lk = lg * 8;

  const int orig = blockIdx.x;
  const int wg = (orig & 7) * 128 + (orig >> 3);  // 8 XCDs x 128 blocks: 4 bh per XCD
  const int qt = wg & 31;
  const int bh = wg >> 5;
  const int b = bh >> 4, h = bh & 15;
  const int q0 = qt * 64;

  const float LOG2E = 1.4426950408889634f;
  const float isq2 = 0.125f * LOG2E;                       // 1/sqrt(64) * log2(e)
  const float slope2 = fexp2(-0.5f * (float)(h + 1)) * LOG2E;

  const u16* Kb = Y + (size_t)b * T_DIM * Y_LD + 1024 + h * DH;
  const u16* Vb = Vt + (size_t)bh * DH * T_DIM;

  // Q fragments in registers for the whole block
  const int qrow = q0 + wave * 16 + lr;
  bf16x8 qf[2];
#pragma unroll
  for (int kk = 0; kk < 2; ++kk)
    qf[kk] = *reinterpret_cast<const bf16x8*>(
        &Y[(size_t)(b * T_DIM + qrow) * Y_LD + h * DH + kk * 32 + lk]);

  int qg[4]; float aq2[4];
#pragma unroll
  for (int r = 0; r < 4; ++r) {
    qg[r] = q0 + wave * 16 + lg * 4 + r;
    aq2[r] = slope2 * (float)qg[r];
  }

  f32x4 oacc[4] = {};
  float mrow[4], lrow[4];
#pragma unroll
  for (int r = 0; r < 4; ++r) { mrow[r] = -INFINITY; lrow[r] = 0.f; }

  u16* Plw = Pl + wave * 16 * 72;

  for (int kt = 0; kt <= qt; ++kt) {
    const int kv0 = kt * 64;
    // S = Q K^T
    f32x4 sacc[4] = {};
#pragma unroll
    for (int kk = 0; kk < 2; ++kk)
#pragma unroll
      for (int ni = 0; ni < 4; ++ni) {
        bf16x8 kf = *reinterpret_cast<const bf16x8*>(
            Kb + (size_t)(kv0 + ni * 16 + lr) * Y_LD + kk * 32 + lk);
        sacc[ni] = __builtin_amdgcn_mfma_f32_16x16x32_bf16(qf[kk], kf, sacc[ni], 0, 0, 0);
      }
    // scale + alibi (+ causal on diagonal tile), log2 domain
    float pv[4][4], rmax4[4];
#pragma unroll
    for (int r = 0; r < 4; ++r) rmax4[r] = -INFINITY;
    const bool diag = (kt == qt);
#pragma unroll
    for (int ni = 0; ni < 4; ++ni) {
      const int kg = kv0 + ni * 16 + lr;
      const float ak = slope2 * (float)kg;
#pragma unroll
      for (int r = 0; r < 4; ++r) {
        float s = fmaf(sacc[ni][r], isq2, aq2[r] - ak);
        if (diag && kg > qg[r]) s = -INFINITY;
        pv[ni][r] = s;
        rmax4[r] = fmaxf(rmax4[r], s);
      }
    }
#pragma unroll
    for (int r = 0; r < 4; ++r) {
#pragma unroll
      for (int off = 1; off < 16; off <<= 1)
        rmax4[r] = fmaxf(rmax4[r], __shfl_xor(rmax4[r], off));
    }
    // defer-max (T13): skip rescale when max growth bounded (exp2 arg <= 11)
    int ok = (rmax4[0] - mrow[0] <= 11.f) && (rmax4[1] - mrow[1] <= 11.f) &&
             (rmax4[2] - mrow[2] <= 11.f) && (rmax4[3] - mrow[3] <= 11.f);
    if (!__all(ok)) {
#pragma unroll
      for (int r = 0; r < 4; ++r) {
        float mn = fmaxf(mrow[r], rmax4[r]);
        float al = fexp2(mrow[r] - mn);     // first tile: exp2(-inf)=0
        mrow[r] = mn;
        lrow[r] *= al;
#pragma unroll
        for (int f = 0; f < 4; ++f) oacc[f][r] *= al;
      }
    }
    float rsum[4] = {0.f, 0.f, 0.f, 0.f};
#pragma unroll
    for (int ni = 0; ni < 4; ++ni)
#pragma unroll
      for (int r = 0; r < 4; ++r) {
        float p = fexp2(pv[ni][r] - mrow[r]);   // masked -> 0
        rsum[r] += p;
        Plw[swzp(lg * 4 + r, ni * 16 + lr)] = f2bf(p);
      }
#pragma unroll
    for (int r = 0; r < 4; ++r) {
#pragma unroll
      for (int off = 1; off < 16; off <<= 1)
        rsum[r] += __shfl_xor(rsum[r], off);
      lrow[r] += rsum[r];
    }
    asm volatile("" ::: "memory");  // P writes before P reads (same-wave DS is in-order)
    // O += P @ V  (V^T fragments straight from global / L2)
#pragma unroll
    for (int kk = 0; kk < 2; ++kk) {
      bf16x8 pf = *reinterpret_cast<const bf16x8*>(&Plw[swzp(lr, kk * 32 + lk)]);
#pragma unroll
      for (int f = 0; f < 4; ++f) {
        bf16x8 vf = *reinterpret_cast<const bf16x8*>(
            Vb + (size_t)(f * 16 + lr) * T_DIM + kv0 + kk * 32 + lk);
        oacc[f] = __builtin_amdgcn_mfma_f32_16x16x32_bf16(pf, vf, oacc[f], 0, 0, 0);
      }
    }
    asm volatile("" ::: "memory");  // P reads before next-iter writes
  }
  // normalize + store
#pragma unroll
  for (int f = 0; f < 4; ++f)
#pragma unroll
    for (int r = 0; r < 4; ++r) {
      int q = q0 + wave * 16 + lg * 4 + r;
      float v = oacc[f][r] / lrow[r];
      Og[(size_t)(b * T_DIM + q) * E_DIM + h * DH + f * 16 + lr] = f2bf(v);
    }
}

extern "C" void kernel_launch(void* const* d_in, const int* in_sizes, int n_in,
                              void* d_out, int out_size, void* d_ws, size_t ws_size,
                              hipStream_t stream) {
  const float* x  = (const float*)d_in[0];
  const float* Wq = (const float*)d_in[1];
  const float* Aq = (const float*)d_in[2];
  const float* Bq = (const float*)d_in[3];
  const float* Wk = (const float*)d_in[4];
  const float* Ak = (const float*)d_in[5];
  const float* Bk = (const float*)d_in[6];
  const float* Wv = (const float*)d_in[7];
  const float* Av = (const float*)d_in[8];
  const float* Bv = (const float*)d_in[9];
  const float* Wp = (const float*)d_in[10];
  float* out = (float*)d_out;

  char* ws = (char*)d_ws;
  u16* xb   = (u16*)(ws);                        // 4096x1024 bf16  (8 MB)
  u16* VtB  = (u16*)(ws);                        // reuses xb region after QKV GEMM
  u16* Weff = (u16*)(ws + 8388608);              // 3x1024x1024 bf16 (6 MB)
  u16* Wpb  = (u16*)(ws + 14680064);             // 1024x1024 bf16  (2 MB)
  u16* Yq   = (u16*)(ws + 16777216);             // 4096x3072 bf16  (24 MB)
  u16* Og   = (u16*)(ws + 41943040);             // 4096x1024 bf16  (8 MB)

  // 1) cast x to bf16
  k_cast_bf16<<<4096, 256, 0, stream>>>(x, xb, BT * E_DIM);
  // 2) fold LoRA: Weff = W + 2*A@B  (q,k,v stacked)
  k_weff<<<4096, 256, 0, stream>>>(Wq, Aq, Bq, Weff);
  k_weff<<<4096, 256, 0, stream>>>(Wk, Ak, Bk, Weff + 1024 * 1024);
  k_weff<<<4096, 256, 0, stream>>>(Wv, Av, Bv, Weff + 2 * 1024 * 1024);
  // 3) cast Wp
  k_cast_bf16<<<1024, 256, 0, stream>>>(Wp, Wpb, E_DIM * E_DIM);
  // 4) fused QKV GEMM: Y = xb @ Weff^T   [4096 x 3072]
  {
    dim3 grid(Y_LD / 128, BT / 128);
    k_gemm_bt<u16><<<grid, 256, 0, stream>>>(xb, Weff, Yq, E_DIM, Y_LD);
  }
  // 5) transpose V (xb region is dead now)
  {
    dim3 grid(T_DIM / 64, 2 * H_NUM);
    k_vtrans<<<grid, 256, 0, stream>>>(Yq, VtB);
  }
  // 6) attention
  k_attn2<<<1024, 256, 0, stream>>>(Yq, VtB, Og);
  // 7) output projection: out = Og @ Wp^T  (fp32 out)
  {
    dim3 grid(E_DIM / 128, BT / 128);
    k_gemm_bt<float><<<grid, 256, 0, stream>>>(Og, Wpb, out, E_DIM, E_DIM);
  }
}

// Round 3
// 151.713 us; speedup vs baseline: 2.0503x; 1.6910x over previous
//
#include <hip/hip_runtime.h>

typedef unsigned short u16;
typedef unsigned int   u32;
typedef __bf16 bf16_t;
typedef bf16_t bf16x8 __attribute__((ext_vector_type(8)));
typedef float  f32x4  __attribute__((ext_vector_type(4)));

#define E_DIM 1024
#define T_DIM 2048
#define H_NUM 16
#define DH 64
#define BT 4096          // B*T
#define Y_LD 3072        // QKV fused row stride

__device__ __forceinline__ u16 f2bf(float f) {
  u32 u = __builtin_bit_cast(u32, f);
  u32 r = (u + 0x7fffu + ((u >> 16) & 1u)) >> 16;
  return (u16)r;
}
// cheap round-half-up (differs from RNE only on exact ties)
__device__ __forceinline__ u16 f2bf_p(float f) {
  u32 u = __builtin_bit_cast(u32, f);
  return (u16)((u + 0x8000u) >> 16);
}

__device__ __forceinline__ float fexp2(float x) {
#if __has_builtin(__builtin_amdgcn_exp2f)
  return __builtin_amdgcn_exp2f(x);
#else
  return exp2f(x);
#endif
}

// XOR swizzle for [R][64]-element bf16 LDS tiles (row = 128B).
__device__ __forceinline__ int swz(int r, int c) {
  return r * 64 + (c ^ ((r & 7) << 3));
}
// P-tile swizzle with 72-element row stride.
__device__ __forceinline__ int swzp(int r, int c) {
  return r * 72 + (c ^ ((r & 7) << 3));
}

__device__ __forceinline__ void store_val(float* p, float v) { *p = v; }
__device__ __forceinline__ void store_val(u16* p, float v)   { *p = f2bf(v); }

typedef __attribute__((address_space(3))) unsigned int as3_u32;
typedef const __attribute__((address_space(1))) unsigned int as1_u32;

__device__ __forceinline__ void async16(const u16* g, u16* l) {
  __builtin_amdgcn_global_load_lds((as1_u32*)g, (as3_u32*)l, 16, 0, 0);
}

// ---------------- prep kernels ----------------
__global__ void k_cast_bf16(const float* __restrict__ in, u16* __restrict__ out, int n) {
  int i = (blockIdx.x * blockDim.x + threadIdx.x) * 4;
  if (i + 3 < n) {
    float4 v = *reinterpret_cast<const float4*>(in + i);
    u32 lo = (u32)f2bf(v.x) | ((u32)f2bf(v.y) << 16);
    u32 hi = (u32)f2bf(v.z) | ((u32)f2bf(v.w) << 16);
    *reinterpret_cast<uint2*>(out + i) = make_uint2(lo, hi);
  }
}

// Weff[o][i] = (W[o][i] + 2 * sum_r A[o][r] * Bm[r][i]) * scale
__global__ void k_weff(const float* __restrict__ W, const float* __restrict__ A,
                       const float* __restrict__ Bm, u16* __restrict__ out, float scale) {
  int idx = blockIdx.x * blockDim.x + threadIdx.x;
  int o = idx >> 10, i = idx & 1023;
  float acc = W[idx];
#pragma unroll
  for (int r = 0; r < 8; ++r) acc += 2.0f * A[o * 8 + r] * Bm[r * 1024 + i];
  out[idx] = f2bf(acc * scale);
}

// V transpose: Vt[b][h][d][t]  <-  Y[(b*T+t)*3072 + 2048 + h*64 + d]
__global__ __launch_bounds__(256) void k_vtrans(const u16* __restrict__ Y, u16* __restrict__ Vt) {
  __shared__ u16 tile[64 * 65];
  const int tid = threadIdx.x;
  const int bh = blockIdx.y;
  const int b = bh >> 4, h = bh & 15;
  const int t0 = blockIdx.x * 64;
  const u16* src = Y + (size_t)(b * T_DIM + t0) * Y_LD + 2048 + h * DH;
#pragma unroll
  for (int p = 0; p < 2; ++p) {
    int idx = p * 256 + tid;
    int tr = idx >> 3, dc = (idx & 7) * 8;
    uint4 v = *reinterpret_cast<const uint4*>(src + (size_t)tr * Y_LD + dc);
    const u16* e = reinterpret_cast<const u16*>(&v);
#pragma unroll
    for (int j = 0; j < 8; ++j) tile[tr * 65 + dc + j] = e[j];
  }
  __syncthreads();
  u16* dst = Vt + (size_t)bh * DH * T_DIM + t0;
#pragma unroll
  for (int p = 0; p < 2; ++p) {
    int idx = p * 256 + tid;
    int dr = idx >> 3, tc = (idx & 7) * 8;
    u16 tmp[8];
#pragma unroll
    for (int j = 0; j < 8; ++j) tmp[j] = tile[(tc + j) * 65 + dr];
    *reinterpret_cast<uint4*>(dst + (size_t)dr * T_DIM + tc) = *reinterpret_cast<const uint4*>(tmp);
  }
}

// ---------------- GEMM: C[m][n] = sum_k A[m][k] * B[n][k] ----------------
template <typename OUT_T>
__global__ __launch_bounds__(256) void k_gemm_bt(
    const u16* __restrict__ A, const u16* __restrict__ B,
    OUT_T* __restrict__ C, int K, int ldc) {
  __shared__ __align__(16) u16 As[128 * 64];
  __shared__ __align__(16) u16 Bs[128 * 64];
  const int tid  = threadIdx.x;
  const int lane = tid & 63;
  const int wave = tid >> 6;
  const int wr = wave >> 1, wc = wave & 1;
  const int m0 = blockIdx.y * 128;
  const int n0 = blockIdx.x * 128;
  const int lr = lane & 15;
  const int lk = (lane >> 4) * 8;

  f32x4 acc[4][4] = {};

  for (int k0 = 0; k0 < K; k0 += 64) {
    __syncthreads();
#pragma unroll
    for (int p = 0; p < 4; ++p) {
      const int off = (p * 4 + wave) * 512;
      const int e = off + lane * 8;
      const int r = e >> 6, c = e & 63;
      const int cs = c ^ ((r & 7) << 3);
      async16(&A[(size_t)(m0 + r) * K + k0 + cs], As + off);
      async16(&B[(size_t)(n0 + r) * K + k0 + cs], Bs + off);
    }
    __syncthreads();
#pragma unroll
    for (int kk = 0; kk < 2; ++kk) {
      bf16x8 af[4], bfr[4];
#pragma unroll
      for (int mi = 0; mi < 4; ++mi)
        af[mi] = *reinterpret_cast<const bf16x8*>(&As[swz(wr * 64 + mi * 16 + lr, kk * 32 + lk)]);
#pragma unroll
      for (int ni = 0; ni < 4; ++ni)
        bfr[ni] = *reinterpret_cast<const bf16x8*>(&Bs[swz(wc * 64 + ni * 16 + lr, kk * 32 + lk)]);
#pragma unroll
      for (int mi = 0; mi < 4; ++mi)
#pragma unroll
        for (int ni = 0; ni < 4; ++ni)
          acc[mi][ni] = __builtin_amdgcn_mfma_f32_16x16x32_bf16(af[mi], bfr[ni], acc[mi][ni], 0, 0, 0);
    }
  }
  const int rg = (lane >> 4) * 4;
#pragma unroll
  for (int mi = 0; mi < 4; ++mi)
#pragma unroll
    for (int ni = 0; ni < 4; ++ni)
#pragma unroll
      for (int q = 0; q < 4; ++q) {
        int row = m0 + wr * 64 + mi * 16 + rg + q;
        int col = n0 + wc * 64 + ni * 16 + lr;
        store_val(&C[(size_t)row * ldc + col], acc[mi][ni][q]);
      }
}

// ---------------- paired, double-buffered flash attention ----------------
// grid 512 (XCD-remapped). Block owns q-tiles lo=pr, hi=31-pr (33 tile-computes
// per block, balanced). K/V tiles staged in LDS via global_load_lds, shared by
// 4 waves and both q-tiles. Softmax in shifted log2 domain w/ lazy max and
// deferred row-sum.
__device__ __forceinline__ void softmax_tile(
    const f32x4 sacc[4], const float aq2r[4], float mrow[4], float lsum[4],
    f32x4 oaccr[4], const float nalk[4], float ckt, bool diag, int wq,
    int lg, int lr, u16* Plw) {
  float pv[4][4], a2[4], lmax[4];
#pragma unroll
  for (int r = 0; r < 4; ++r) { a2[r] = aq2r[r] - ckt - mrow[r]; lmax[r] = -3.0e38f; }
#pragma unroll
  for (int ni = 0; ni < 4; ++ni) {
    const int kl = ni * 16 + lr;
#pragma unroll
    for (int r = 0; r < 4; ++r) {
      float s = sacc[ni][r] + a2[r] + nalk[ni];   // = score - mrow (shifted)
      if (diag && kl > wq + lg * 4 + r) s = -INFINITY;
      pv[ni][r] = s;
      lmax[r] = fmaxf(lmax[r], s);
    }
  }
  bool ok = lmax[0] <= 11.f && lmax[1] <= 11.f && lmax[2] <= 11.f && lmax[3] <= 11.f;
  if (!__all((int)ok)) {
#pragma unroll
    for (int r = 0; r < 4; ++r) {
      float m = lmax[r];
#pragma unroll
      for (int off = 1; off < 16; off <<= 1) m = fmaxf(m, __shfl_xor(m, off));
      float msc = fmaxf(m, 0.f);          // shift amount to apply now
      float al = fexp2(-msc);
      mrow[r] += msc;
      lsum[r] *= al;
#pragma unroll
      for (int f = 0; f < 4; ++f) oaccr[f][r] *= al;
#pragma unroll
      for (int ni = 0; ni < 4; ++ni) pv[ni][r] -= msc;
    }
  }
#pragma unroll
  for (int ni = 0; ni < 4; ++ni)
#pragma unroll
    for (int r = 0; r < 4; ++r) {
      float p = fexp2(pv[ni][r]);          // bounded by 2^11 (defer-max)
      lsum[r] += p;
      Plw[swzp(lg * 4 + r, ni * 16 + lr)] = f2bf_p(p);
    }
}

__global__ __launch_bounds__(256) void k_attn3(
    const u16* __restrict__ Y, const u16* __restrict__ Vt, u16* __restrict__ Og) {
  __shared__ __align__(16) u16 Ks[2][4096];
  __shared__ __align__(16) u16 Vs[2][4096];
  __shared__ __align__(16) u16 Pl[4][2][16 * 72];

  const int tid = threadIdx.x;
  const int lane = tid & 63;
  const int wave = tid >> 6;
  const int lr = lane & 15;
  const int lg = lane >> 4;
  const int lk = lg * 8;

  const int orig = blockIdx.x;
  const int wg = (orig & 7) * 64 + (orig >> 3);   // XCD-chunked remap (512%8==0)
  const int bh = wg >> 4;                          // 0..31
  const int pr = wg & 15;                          // 0..15
  const int b = bh >> 4, h = bh & 15;
  const int tlo = pr, thi = 31 - pr;

  const float LOG2E = 1.4426950408889634f;
  const float slope2 = exp2f(-0.5f * (float)(h + 1)) * LOG2E;

  const u16* Kb = Y + (size_t)b * T_DIM * Y_LD + 1024 + h * DH;
  const u16* Vb = Vt + (size_t)bh * DH * T_DIM;

  // Q fragments (Q pre-scaled by 1/sqrt(dh)*log2e in k_weff)
  bf16x8 qf[2][2];
  const int tqarr[2] = {tlo, thi};
#pragma unroll
  for (int t = 0; t < 2; ++t) {
    const int qrow = tqarr[t] * 64 + wave * 16 + lr;
#pragma unroll
    for (int kk = 0; kk < 2; ++kk)
      qf[t][kk] = *reinterpret_cast<const bf16x8*>(
          &Y[(size_t)(b * T_DIM + qrow) * Y_LD + h * DH + kk * 32 + lk]);
  }

  float aq2[2][4], nalk[4];
#pragma unroll
  for (int ni = 0; ni < 4; ++ni) nalk[ni] = -slope2 * (float)(ni * 16 + lr);
#pragma unroll
  for (int t = 0; t < 2; ++t)
#pragma unroll
    for (int r = 0; r < 4; ++r)
      aq2[t][r] = slope2 * (float)(tqarr[t] * 64 + wave * 16 + lg * 4 + r);

  f32x4 oacc[2][4] = {};
  float mrow[2][4] = {};   // finite init (0): safe, lazy-max bounds p by 2^11
  float lsum[2][4] = {};

  auto stage = [&](int bufi, int kt) {
    const int kv0 = kt * 64;
#pragma unroll
    for (int q = 0; q < 2; ++q) {
      const int off = (q * 4 + wave) * 512;
      const int e = off + lane * 8;
      const int r = e >> 6, c = e & 63;
      const int cs = c ^ ((r & 7) << 3);
      async16(Kb + (size_t)(kv0 + r) * Y_LD + cs, &Ks[bufi][off]);
      async16(Vb + (size_t)r * T_DIM + kv0 + cs, &Vs[bufi][off]);
    }
  };

  stage(0, 0);
  __syncthreads();
  int buf = 0;

  for (int kt = 0; kt <= thi; ++kt) {
    if (kt < thi) stage(buf ^ 1, kt + 1);
    const bool dolo = (kt <= tlo);
    // QK^T for both tiles, sharing kf
    f32x4 sh[4] = {}, sl[4] = {};
#pragma unroll
    for (int kk = 0; kk < 2; ++kk)
#pragma unroll
      for (int ni = 0; ni < 4; ++ni) {
        bf16x8 kf = *reinterpret_cast<const bf16x8*>(&Ks[buf][swz(ni * 16 + lr, kk * 32 + lk)]);
        sh[ni] = __builtin_amdgcn_mfma_f32_16x16x32_bf16(qf[1][kk], kf, sh[ni], 0, 0, 0);
        if (dolo) sl[ni] = __builtin_amdgcn_mfma_f32_16x16x32_bf16(qf[0][kk], kf, sl[ni], 0, 0, 0);
      }
    const float ckt = slope2 * (float)(kt * 64);
    softmax_tile(sh, aq2[1], mrow[1], lsum[1], oacc[1], nalk, ckt, kt == thi,
                 wave * 16, lg, lr, &Pl[wave][1][0]);
    if (dolo)
      softmax_tile(sl, aq2[0], mrow[0], lsum[0], oacc[0], nalk, ckt, kt == tlo,
                   wave * 16, lg, lr, &Pl[wave][0][0]);
    asm volatile("" ::: "memory");
    // PV for both tiles, sharing vf
#pragma unroll
    for (int kk = 0; kk < 2; ++kk) {
      bf16x8 ph = *reinterpret_cast<const bf16x8*>(&Pl[wave][1][swzp(lr, kk * 32 + lk)]);
      bf16x8 pl = ph;
      if (dolo) pl = *reinterpret_cast<const bf16x8*>(&Pl[wave][0][swzp(lr, kk * 32 + lk)]);
#pragma unroll
      for (int f = 0; f < 4; ++f) {
        bf16x8 vf = *reinterpret_cast<const bf16x8*>(&Vs[buf][swz(f * 16 + lr, kk * 32 + lk)]);
        oacc[1][f] = __builtin_amdgcn_mfma_f32_16x16x32_bf16(ph, vf, oacc[1][f], 0, 0, 0);
        if (dolo) oacc[0][f] = __builtin_amdgcn_mfma_f32_16x16x32_bf16(pl, vf, oacc[0][f], 0, 0, 0);
      }
    }
    __syncthreads();
    buf ^= 1;
  }

  // deferred row-sum reduce, normalize, store
  float linv[2][4];
#pragma unroll
  for (int t = 0; t < 2; ++t)
#pragma unroll
    for (int r = 0; r < 4; ++r) {
      float s = lsum[t][r];
#pragma unroll
      for (int off = 1; off < 16; off <<= 1) s += __shfl_xor(s, off);
      linv[t][r] = 1.0f / s;
    }
#pragma unroll
  for (int t = 0; t < 2; ++t)
#pragma unroll
    for (int f = 0; f < 4; ++f)
#pragma unroll
      for (int r = 0; r < 4; ++r) {
        int q = tqarr[t] * 64 + wave * 16 + lg * 4 + r;
        Og[(size_t)(b * T_DIM + q) * E_DIM + h * DH + f * 16 + lr] =
            f2bf(oacc[t][f][r] * linv[t][r]);
      }
}

extern "C" void kernel_launch(void* const* d_in, const int* in_sizes, int n_in,
                              void* d_out, int out_size, void* d_ws, size_t ws_size,
                              hipStream_t stream) {
  const float* x  = (const float*)d_in[0];
  const float* Wq = (const float*)d_in[1];
  const float* Aq = (const float*)d_in[2];
  const float* Bq = (const float*)d_in[3];
  const float* Wk = (const float*)d_in[4];
  const float* Ak = (const float*)d_in[5];
  const float* Bk = (const float*)d_in[6];
  const float* Wv = (const float*)d_in[7];
  const float* Av = (const float*)d_in[8];
  const float* Bv = (const float*)d_in[9];
  const float* Wp = (const float*)d_in[10];
  float* out = (float*)d_out;

  char* ws = (char*)d_ws;
  u16* xb   = (u16*)(ws);                        // 4096x1024 bf16  (8 MB)
  u16* VtB  = (u16*)(ws);                        // reuses xb region after QKV GEMM
  u16* Weff = (u16*)(ws + 8388608);              // 3x1024x1024 bf16 (6 MB)
  u16* Wpb  = (u16*)(ws + 14680064);             // 1024x1024 bf16  (2 MB)
  u16* Yq   = (u16*)(ws + 16777216);             // 4096x3072 bf16  (24 MB)
  u16* Og   = (u16*)(ws + 41943040);             // 4096x1024 bf16  (8 MB)

  const float ISQ2 = 0.125f * 1.4426950408889634f;  // 1/sqrt(dh) * log2(e)

  k_cast_bf16<<<4096, 256, 0, stream>>>(x, xb, BT * E_DIM);
  k_weff<<<4096, 256, 0, stream>>>(Wq, Aq, Bq, Weff, ISQ2);            // Q pre-scaled
  k_weff<<<4096, 256, 0, stream>>>(Wk, Ak, Bk, Weff + 1024 * 1024, 1.0f);
  k_weff<<<4096, 256, 0, stream>>>(Wv, Av, Bv, Weff + 2 * 1024 * 1024, 1.0f);
  k_cast_bf16<<<1024, 256, 0, stream>>>(Wp, Wpb, E_DIM * E_DIM);
  {
    dim3 grid(Y_LD / 128, BT / 128);
    k_gemm_bt<u16><<<grid, 256, 0, stream>>>(xb, Weff, Yq, E_DIM, Y_LD);
  }
  {
    dim3 grid(T_DIM / 64, 2 * H_NUM);
    k_vtrans<<<grid, 256, 0, stream>>>(Yq, VtB);
  }
  k_attn3<<<512, 256, 0, stream>>>(Yq, VtB, Og);
  {
    dim3 grid(E_DIM / 128, BT / 128);
    k_gemm_bt<float><<<grid, 256, 0, stream>>>(Og, Wpb, out, E_DIM, E_DIM);
  }
}

// Round 4
// 144.817 us; speedup vs baseline: 2.1479x; 1.0476x over previous
//
#include <hip/hip_runtime.h>

typedef unsigned short u16;
typedef unsigned int   u32;
typedef __bf16 bf16_t;
typedef bf16_t bf16x8 __attribute__((ext_vector_type(8)));
typedef float  f32x4  __attribute__((ext_vector_type(4)));

#define E_DIM 1024
#define T_DIM 2048
#define H_NUM 16
#define DH 64
#define BT 4096          // B*T
#define Y_LD 3072        // QKV fused row stride

__device__ __forceinline__ u16 f2bf(float f) {
  u32 u = __builtin_bit_cast(u32, f);
  u32 r = (u + 0x7fffu + ((u >> 16) & 1u)) >> 16;
  return (u16)r;
}

__device__ __forceinline__ float fexp2(float x) {
#if __has_builtin(__builtin_amdgcn_exp2f)
  return __builtin_amdgcn_exp2f(x);
#else
  return exp2f(x);
#endif
}

// XOR swizzle for [R][64]-element bf16 LDS tiles (row = 128B).
__device__ __forceinline__ int swz(int r, int c) {
  return r * 64 + (c ^ ((r & 7) << 3));
}
// P-tile swizzle with 72-element row stride (write b64 / read b128 compatible).
__device__ __forceinline__ int swzp(int r, int c) {
  return r * 72 + (c ^ ((r & 7) << 3));
}

__device__ __forceinline__ void store_val(float* p, float v) { *p = v; }
__device__ __forceinline__ void store_val(u16* p, float v)   { *p = f2bf(v); }

typedef __attribute__((address_space(3))) unsigned int as3_u32;
typedef const __attribute__((address_space(1))) unsigned int as1_u32;

__device__ __forceinline__ void async16(const u16* g, u16* l) {
  __builtin_amdgcn_global_load_lds((as1_u32*)g, (as3_u32*)l, 16, 0, 0);
}

// ---------------- prep kernels ----------------
__global__ void k_cast_bf16(const float* __restrict__ in, u16* __restrict__ out, int n) {
  int i = (blockIdx.x * blockDim.x + threadIdx.x) * 4;
  if (i + 3 < n) {
    float4 v = *reinterpret_cast<const float4*>(in + i);
    u32 lo = (u32)f2bf(v.x) | ((u32)f2bf(v.y) << 16);
    u32 hi = (u32)f2bf(v.z) | ((u32)f2bf(v.w) << 16);
    *reinterpret_cast<uint2*>(out + i) = make_uint2(lo, hi);
  }
}

// All three LoRA folds in one launch: Weff[m] = (W + 2*A@B) * scale_m
__global__ void k_weff3(const float* __restrict__ W0, const float* __restrict__ A0, const float* __restrict__ B0,
                        const float* __restrict__ W1, const float* __restrict__ A1, const float* __restrict__ B1,
                        const float* __restrict__ W2, const float* __restrict__ A2, const float* __restrict__ B2,
                        u16* __restrict__ out, float s0) {
  int idx = blockIdx.x * blockDim.x + threadIdx.x;
  int m = idx >> 20;                    // matrix id (blocks never straddle)
  int e = idx & 1048575;
  const float* W = (m == 0) ? W0 : (m == 1) ? W1 : W2;
  const float* A = (m == 0) ? A0 : (m == 1) ? A1 : A2;
  const float* Bm = (m == 0) ? B0 : (m == 1) ? B1 : B2;
  const float sc = (m == 0) ? s0 : 1.0f;
  int o = e >> 10, i = e & 1023;
  float acc = W[e];
#pragma unroll
  for (int r = 0; r < 8; ++r) acc += 2.0f * A[o * 8 + r] * Bm[r * 1024 + i];
  out[idx] = f2bf(acc * sc);
}

// V transpose: Vt[b][h][d][t]  <-  Y[(b*T+t)*3072 + 2048 + h*64 + d]
__global__ __launch_bounds__(256) void k_vtrans(const u16* __restrict__ Y, u16* __restrict__ Vt) {
  __shared__ u16 tile[64 * 65];
  const int tid = threadIdx.x;
  const int bh = blockIdx.y;
  const int b = bh >> 4, h = bh & 15;
  const int t0 = blockIdx.x * 64;
  const u16* src = Y + (size_t)(b * T_DIM + t0) * Y_LD + 2048 + h * DH;
#pragma unroll
  for (int p = 0; p < 2; ++p) {
    int idx = p * 256 + tid;
    int tr = idx >> 3, dc = (idx & 7) * 8;
    uint4 v = *reinterpret_cast<const uint4*>(src + (size_t)tr * Y_LD + dc);
    const u16* e = reinterpret_cast<const u16*>(&v);
#pragma unroll
    for (int j = 0; j < 8; ++j) tile[tr * 65 + dc + j] = e[j];
  }
  __syncthreads();
  u16* dst = Vt + (size_t)bh * DH * T_DIM + t0;
#pragma unroll
  for (int p = 0; p < 2; ++p) {
    int idx = p * 256 + tid;
    int dr = idx >> 3, tc = (idx & 7) * 8;
    u16 tmp[8];
#pragma unroll
    for (int j = 0; j < 8; ++j) tmp[j] = tile[(tc + j) * 65 + dr];
    *reinterpret_cast<uint4*>(dst + (size_t)dr * T_DIM + tc) = *reinterpret_cast<const uint4*>(tmp);
  }
}

// ---------------- GEMM: C[m][n] = sum_k A[m][k] * B[n][k] ----------------
template <typename OUT_T>
__global__ __launch_bounds__(256) void k_gemm_bt(
    const u16* __restrict__ A, const u16* __restrict__ B,
    OUT_T* __restrict__ C, int K, int ldc) {
  __shared__ __align__(16) u16 As[128 * 64];
  __shared__ __align__(16) u16 Bs[128 * 64];
  const int tid  = threadIdx.x;
  const int lane = tid & 63;
  const int wave = tid >> 6;
  const int wr = wave >> 1, wc = wave & 1;
  const int m0 = blockIdx.y * 128;
  const int n0 = blockIdx.x * 128;
  const int lr = lane & 15;
  const int lk = (lane >> 4) * 8;

  f32x4 acc[4][4] = {};

  for (int k0 = 0; k0 < K; k0 += 64) {
    __syncthreads();
#pragma unroll
    for (int p = 0; p < 4; ++p) {
      const int off = (p * 4 + wave) * 512;
      const int e = off + lane * 8;
      const int r = e >> 6, c = e & 63;
      const int cs = c ^ ((r & 7) << 3);
      async16(&A[(size_t)(m0 + r) * K + k0 + cs], As + off);
      async16(&B[(size_t)(n0 + r) * K + k0 + cs], Bs + off);
    }
    __syncthreads();
#pragma unroll
    for (int kk = 0; kk < 2; ++kk) {
      bf16x8 af[4], bfr[4];
#pragma unroll
      for (int mi = 0; mi < 4; ++mi)
        af[mi] = *reinterpret_cast<const bf16x8*>(&As[swz(wr * 64 + mi * 16 + lr, kk * 32 + lk)]);
#pragma unroll
      for (int ni = 0; ni < 4; ++ni)
        bfr[ni] = *reinterpret_cast<const bf16x8*>(&Bs[swz(wc * 64 + ni * 16 + lr, kk * 32 + lk)]);
#pragma unroll
      for (int mi = 0; mi < 4; ++mi)
#pragma unroll
        for (int ni = 0; ni < 4; ++ni)
          acc[mi][ni] = __builtin_amdgcn_mfma_f32_16x16x32_bf16(af[mi], bfr[ni], acc[mi][ni], 0, 0, 0);
    }
  }
  const int rg = (lane >> 4) * 4;
#pragma unroll
  for (int mi = 0; mi < 4; ++mi)
#pragma unroll
    for (int ni = 0; ni < 4; ++ni)
#pragma unroll
      for (int q = 0; q < 4; ++q) {
        int row = m0 + wr * 64 + mi * 16 + rg + q;
        int col = n0 + wc * 64 + ni * 16 + lr;
        store_val(&C[(size_t)row * ldc + col], acc[mi][ni][q]);
      }
}

// ---------------- fixed-shift flash attention (no online max) ----------------
// ALiBi structure: score = sacc + slope2*(q-k); shifting by (slope2*q + 12)
// cancels q entirely: shifted = sacc - slope2*k - 12.  No max tracking, no
// rescale, no shuffles.  QK^T computed SWAPPED (mfma(kf,qf) -> S^T) so each
// lane holds 4 consecutive k for one q: P written as ds_write_b64, read back
// as the PV A-operand via ds_read_b128.  Row-sums via MFMA with B=ones, which
// lands denominators in the oacc row layout.
__global__ __launch_bounds__(256) void k_attn4(
    const u16* __restrict__ Y, const u16* __restrict__ Vt, u16* __restrict__ Og) {
  __shared__ __align__(16) u16 Ks[2][4096];
  __shared__ __align__(16) u16 Vs[2][4096];
  __shared__ __align__(16) u16 Pl[4][2][16 * 72];

  const int tid = threadIdx.x;
  const int lane = tid & 63;
  const int wave = tid >> 6;
  const int lr = lane & 15;
  const int lg = lane >> 4;
  const int lk = lg * 8;

  const int orig = blockIdx.x;
  const int wg = (orig & 7) * 64 + (orig >> 3);   // XCD-chunked remap (512%8==0)
  const int bh = wg >> 4;                          // 0..31
  const int pr = wg & 15;                          // 0..15
  const int b = bh >> 4, h = bh & 15;
  const int tlo = pr, thi = 31 - pr;

  const float LOG2E = 1.4426950408889634f;
  const float slope2 = exp2f(-0.5f * (float)(h + 1)) * LOG2E;

  const u16* Kb = Y + (size_t)b * T_DIM * Y_LD + 1024 + h * DH;
  const u16* Vb = Vt + (size_t)bh * DH * T_DIM;

  const int tqarr[2] = {tlo, thi};
  // Q fragments (pre-scaled by 1/sqrt(dh)*log2e); used as the MFMA B-operand.
  bf16x8 qf[2][2];
#pragma unroll
  for (int t = 0; t < 2; ++t) {
    const int qrow = tqarr[t] * 64 + wave * 16 + lr;
#pragma unroll
    for (int kk = 0; kk < 2; ++kk)
      qf[t][kk] = *reinterpret_cast<const bf16x8*>(
          &Y[(size_t)(b * T_DIM + qrow) * Y_LD + h * DH + kk * 32 + lk]);
  }

  // per-lane additive constants: nkb[j] = -slope2*k_local - 12
  float nkb[16];
#pragma unroll
  for (int ni = 0; ni < 4; ++ni)
#pragma unroll
    for (int r = 0; r < 4; ++r)
      nkb[ni * 4 + r] = -slope2 * (float)(ni * 16 + lg * 4 + r) - 12.0f;

  bf16x8 ones;
#pragma unroll
  for (int j = 0; j < 8; ++j) ones[j] = (bf16_t)1.0f;

  f32x4 oacc[2][4] = {};
  f32x4 lacc[2] = {};

  auto stage = [&](int bufi, int kt) {
    const int kv0 = kt * 64;
#pragma unroll
    for (int q = 0; q < 2; ++q) {
      const int off = (q * 4 + wave) * 512;
      const int e = off + lane * 8;
      const int r = e >> 6, c = e & 63;
      const int cs = c ^ ((r & 7) << 3);
      async16(Kb + (size_t)(kv0 + r) * Y_LD + cs, &Ks[bufi][off]);
      async16(Vb + (size_t)r * T_DIM + kv0 + cs, &Vs[bufi][off]);
    }
  };

  stage(0, 0);
  __syncthreads();
  int buf = 0;

  for (int kt = 0; kt <= thi; ++kt) {
    if (kt < thi) stage(buf ^ 1, kt + 1);
    const bool dolo = (kt <= tlo);
    // S^T = K Q^T : lane holds k = kv0+ni*16+lg*4+r (reg r), q = q0w+lr (col)
    f32x4 sh[4] = {}, sl[4] = {};
#pragma unroll
    for (int kk = 0; kk < 2; ++kk)
#pragma unroll
      for (int ni = 0; ni < 4; ++ni) {
        bf16x8 kf = *reinterpret_cast<const bf16x8*>(&Ks[buf][swz(ni * 16 + lr, kk * 32 + lk)]);
        sh[ni] = __builtin_amdgcn_mfma_f32_16x16x32_bf16(kf, qf[1][kk], sh[ni], 0, 0, 0);
        if (dolo) sl[ni] = __builtin_amdgcn_mfma_f32_16x16x32_bf16(kf, qf[0][kk], sl[ni], 0, 0, 0);
      }
    const float ck = -slope2 * (float)(kt * 64);
    // softmax (fixed shift) + pack + P write
#pragma unroll
    for (int t = 0; t < 2; ++t) {
      if (t == 0 && !dolo) continue;
      const f32x4* sa = (t == 0) ? sl : sh;
      const bool diag = (kt == tqarr[t]);
#pragma unroll
      for (int ni = 0; ni < 4; ++ni) {
        u16 pk[4];
#pragma unroll
        for (int r = 0; r < 4; ++r) {
          float s = sa[ni][r] + nkb[ni * 4 + r] + ck;
          if (diag && (ni * 16 + lg * 4 + r) > (wave * 16 + lr)) s = -INFINITY;
          pk[r] = __builtin_bit_cast(u16, (bf16_t)fexp2(s));
        }
        *reinterpret_cast<uint2*>(&Pl[wave][t][swzp(lr, ni * 16 + lg * 4)]) =
            __builtin_bit_cast(uint2, *reinterpret_cast<const ulonglong1*>(pk));
      }
    }
    asm volatile("" ::: "memory");
    // O += P @ V ; denominators via ones-MFMA
#pragma unroll
    for (int kk = 0; kk < 2; ++kk) {
      bf16x8 ph = *reinterpret_cast<const bf16x8*>(&Pl[wave][1][swzp(lr, kk * 32 + lk)]);
      bf16x8 pl = ph;
      if (dolo) pl = *reinterpret_cast<const bf16x8*>(&Pl[wave][0][swzp(lr, kk * 32 + lk)]);
      lacc[1] = __builtin_amdgcn_mfma_f32_16x16x32_bf16(ph, ones, lacc[1], 0, 0, 0);
      if (dolo) lacc[0] = __builtin_amdgcn_mfma_f32_16x16x32_bf16(pl, ones, lacc[0], 0, 0, 0);
#pragma unroll
      for (int f = 0; f < 4; ++f) {
        bf16x8 vf = *reinterpret_cast<const bf16x8*>(&Vs[buf][swz(f * 16 + lr, kk * 32 + lk)]);
        oacc[1][f] = __builtin_amdgcn_mfma_f32_16x16x32_bf16(ph, vf, oacc[1][f], 0, 0, 0);
        if (dolo) oacc[0][f] = __builtin_amdgcn_mfma_f32_16x16x32_bf16(pl, vf, oacc[0][f], 0, 0, 0);
      }
    }
    __syncthreads();
    buf ^= 1;
  }

  // normalize + store (lacc rows align with oacc rows: q = q0w + lg*4 + r)
#pragma unroll
  for (int t = 0; t < 2; ++t) {
    float linv[4];
#pragma unroll
    for (int r = 0; r < 4; ++r) linv[r] = 1.0f / lacc[t][r];
#pragma unroll
    for (int f = 0; f < 4; ++f)
#pragma unroll
      for (int r = 0; r < 4; ++r) {
        int q = tqarr[t] * 64 + wave * 16 + lg * 4 + r;
        Og[(size_t)(b * T_DIM + q) * E_DIM + h * DH + f * 16 + lr] =
            f2bf(oacc[t][f][r] * linv[r]);
      }
  }
}

extern "C" void kernel_launch(void* const* d_in, const int* in_sizes, int n_in,
                              void* d_out, int out_size, void* d_ws, size_t ws_size,
                              hipStream_t stream) {
  const float* x  = (const float*)d_in[0];
  const float* Wq = (const float*)d_in[1];
  const float* Aq = (const float*)d_in[2];
  const float* Bq = (const float*)d_in[3];
  const float* Wk = (const float*)d_in[4];
  const float* Ak = (const float*)d_in[5];
  const float* Bk = (const float*)d_in[6];
  const float* Wv = (const float*)d_in[7];
  const float* Av = (const float*)d_in[8];
  const float* Bv = (const float*)d_in[9];
  const float* Wp = (const float*)d_in[10];
  float* out = (float*)d_out;

  char* ws = (char*)d_ws;
  u16* xb   = (u16*)(ws);                        // 4096x1024 bf16  (8 MB)
  u16* VtB  = (u16*)(ws);                        // reuses xb region after QKV GEMM
  u16* Weff = (u16*)(ws + 8388608);              // 3x1024x1024 bf16 (6 MB)
  u16* Wpb  = (u16*)(ws + 14680064);             // 1024x1024 bf16  (2 MB)
  u16* Yq   = (u16*)(ws + 16777216);             // 4096x3072 bf16  (24 MB)
  u16* Og   = (u16*)(ws + 41943040);             // 4096x1024 bf16  (8 MB)

  const float ISQ2 = 0.125f * 1.4426950408889634f;  // 1/sqrt(dh) * log2(e)

  k_cast_bf16<<<4096, 256, 0, stream>>>(x, xb, BT * E_DIM);
  k_weff3<<<12288, 256, 0, stream>>>(Wq, Aq, Bq, Wk, Ak, Bk, Wv, Av, Bv, Weff, ISQ2);
  k_cast_bf16<<<1024, 256, 0, stream>>>(Wp, Wpb, E_DIM * E_DIM);
  {
    dim3 grid(Y_LD / 128, BT / 128);
    k_gemm_bt<u16><<<grid, 256, 0, stream>>>(xb, Weff, Yq, E_DIM, Y_LD);
  }
  {
    dim3 grid(T_DIM / 64, 2 * H_NUM);
    k_vtrans<<<grid, 256, 0, stream>>>(Yq, VtB);
  }
  k_attn4<<<512, 256, 0, stream>>>(Yq, VtB, Og);
  {
    dim3 grid(E_DIM / 128, BT / 128);
    k_gemm_bt<float><<<grid, 256, 0, stream>>>(Og, Wpb, out, E_DIM, E_DIM);
  }
}

// Round 5
// 136.276 us; speedup vs baseline: 2.2825x; 1.0627x over previous
//
#include <hip/hip_runtime.h>

typedef unsigned short u16;
typedef unsigned int   u32;
typedef __bf16 bf16_t;
typedef bf16_t bf16x8 __attribute__((ext_vector_type(8)));
typedef bf16_t bf16x2v __attribute__((ext_vector_type(2)));
typedef float  f32x4  __attribute__((ext_vector_type(4)));

#define E_DIM 1024
#define T_DIM 2048
#define H_NUM 16
#define DH 64
#define BT 4096          // B*T
#define Y_LD 3072        // QKV fused row stride

__device__ __forceinline__ u16 f2bf(float f) {
  u32 u = __builtin_bit_cast(u32, f);
  u32 r = (u + 0x7fffu + ((u >> 16) & 1u)) >> 16;
  return (u16)r;
}

__device__ __forceinline__ float fexp2(float x) {
#if __has_builtin(__builtin_amdgcn_exp2f)
  return __builtin_amdgcn_exp2f(x);
#else
  return exp2f(x);
#endif
}

// XOR swizzle for [R][64]-element bf16 LDS tiles (row = 128B).
__device__ __forceinline__ int swz(int r, int c) {
  return r * 64 + (c ^ ((r & 7) << 3));
}

__device__ __forceinline__ void store_val(float* p, float v) { *p = v; }
__device__ __forceinline__ void store_val(u16* p, float v)   { *p = f2bf(v); }

typedef __attribute__((address_space(3))) unsigned int as3_u32;
typedef const __attribute__((address_space(1))) unsigned int as1_u32;

__device__ __forceinline__ void async16(const u16* g, u16* l) {
  __builtin_amdgcn_global_load_lds((as1_u32*)g, (as3_u32*)l, 16, 0, 0);
}

// pack two f32 -> one u32 of 2 bf16 (compiler emits v_cvt_pk_bf16_f32)
__device__ __forceinline__ u32 pack2(float a, float b) {
  bf16x2v v;
  v[0] = (bf16_t)a;
  v[1] = (bf16_t)b;
  return __builtin_bit_cast(u32, v);
}

// v_permlane32_swap_b32: a<-[Alo|Blo], b<-[Ahi|Bhi]
__device__ __forceinline__ void plswap(u32& a, u32& b) {
#if __has_builtin(__builtin_amdgcn_permlane32_swap)
  typedef u32 u32x2 __attribute__((ext_vector_type(2)));
  u32x2 r = __builtin_amdgcn_permlane32_swap(a, b, false, false);
  a = r[0];
  b = r[1];
#else
  asm volatile("v_permlane32_swap_b32 %0, %1" : "+v"(a), "+v"(b));
#endif
}

// Redistribute one (A,B)=(pk[2kk][j], pk[2kk+1][j]) pair into fragment words
// wj (k=lg*8+2j) and wj2 (k=lg*8+4+2j).  odd = lane bit 4.
__device__ __forceinline__ void redist_pair(u32 A, u32 B, bool odd, u32& wj, u32& wj2) {
  plswap(A, B);
  u32 sA = __builtin_amdgcn_ds_swizzle(A, 0x401F);  // lane ^ 16
  u32 sB = __builtin_amdgcn_ds_swizzle(B, 0x401F);
  wj  = odd ? sB : A;
  wj2 = odd ? B : sA;
}

// ---------------- prep kernels ----------------
__global__ void k_cast_bf16(const float* __restrict__ in, u16* __restrict__ out, int n) {
  int i = (blockIdx.x * blockDim.x + threadIdx.x) * 4;
  if (i + 3 < n) {
    float4 v = *reinterpret_cast<const float4*>(in + i);
    u32 lo = (u32)f2bf(v.x) | ((u32)f2bf(v.y) << 16);
    u32 hi = (u32)f2bf(v.z) | ((u32)f2bf(v.w) << 16);
    *reinterpret_cast<uint2*>(out + i) = make_uint2(lo, hi);
  }
}

// All three LoRA folds in one launch: Weff[m] = (W + 2*A@B) * scale_m
__global__ void k_weff3(const float* __restrict__ W0, const float* __restrict__ A0, const float* __restrict__ B0,
                        const float* __restrict__ W1, const float* __restrict__ A1, const float* __restrict__ B1,
                        const float* __restrict__ W2, const float* __restrict__ A2, const float* __restrict__ B2,
                        u16* __restrict__ out, float s0) {
  int idx = blockIdx.x * blockDim.x + threadIdx.x;
  int m = idx >> 20;                    // matrix id (blocks never straddle)
  int e = idx & 1048575;
  const float* W = (m == 0) ? W0 : (m == 1) ? W1 : W2;
  const float* A = (m == 0) ? A0 : (m == 1) ? A1 : A2;
  const float* Bm = (m == 0) ? B0 : (m == 1) ? B1 : B2;
  const float sc = (m == 0) ? s0 : 1.0f;
  int o = e >> 10, i = e & 1023;
  float acc = W[e];
#pragma unroll
  for (int r = 0; r < 8; ++r) acc += 2.0f * A[o * 8 + r] * Bm[r * 1024 + i];
  out[idx] = f2bf(acc * sc);
}

// V transpose: Vt[b][h][d][t]  <-  Y[(b*T+t)*3072 + 2048 + h*64 + d]
__global__ __launch_bounds__(256) void k_vtrans(const u16* __restrict__ Y, u16* __restrict__ Vt) {
  __shared__ u16 tile[64 * 65];
  const int tid = threadIdx.x;
  const int bh = blockIdx.y;
  const int b = bh >> 4, h = bh & 15;
  const int t0 = blockIdx.x * 64;
  const u16* src = Y + (size_t)(b * T_DIM + t0) * Y_LD + 2048 + h * DH;
#pragma unroll
  for (int p = 0; p < 2; ++p) {
    int idx = p * 256 + tid;
    int tr = idx >> 3, dc = (idx & 7) * 8;
    uint4 v = *reinterpret_cast<const uint4*>(src + (size_t)tr * Y_LD + dc);
    const u16* e = reinterpret_cast<const u16*>(&v);
#pragma unroll
    for (int j = 0; j < 8; ++j) tile[tr * 65 + dc + j] = e[j];
  }
  __syncthreads();
  u16* dst = Vt + (size_t)bh * DH * T_DIM + t0;
#pragma unroll
  for (int p = 0; p < 2; ++p) {
    int idx = p * 256 + tid;
    int dr = idx >> 3, tc = (idx & 7) * 8;
    u16 tmp[8];
#pragma unroll
    for (int j = 0; j < 8; ++j) tmp[j] = tile[(tc + j) * 65 + dr];
    *reinterpret_cast<uint4*>(dst + (size_t)dr * T_DIM + tc) = *reinterpret_cast<const uint4*>(tmp);
  }
}

// ---------------- GEMM: C[m][n] = sum_k A[m][k] * B[n][k] ----------------
template <typename OUT_T>
__global__ __launch_bounds__(256) void k_gemm_bt(
    const u16* __restrict__ A, const u16* __restrict__ B,
    OUT_T* __restrict__ C, int K, int ldc) {
  __shared__ __align__(16) u16 As[128 * 64];
  __shared__ __align__(16) u16 Bs[128 * 64];
  const int tid  = threadIdx.x;
  const int lane = tid & 63;
  const int wave = tid >> 6;
  const int wr = wave >> 1, wc = wave & 1;
  const int m0 = blockIdx.y * 128;
  const int n0 = blockIdx.x * 128;
  const int lr = lane & 15;
  const int lk = (lane >> 4) * 8;

  f32x4 acc[4][4] = {};

  for (int k0 = 0; k0 < K; k0 += 64) {
    __syncthreads();
#pragma unroll
    for (int p = 0; p < 4; ++p) {
      const int off = (p * 4 + wave) * 512;
      const int e = off + lane * 8;
      const int r = e >> 6, c = e & 63;
      const int cs = c ^ ((r & 7) << 3);
      async16(&A[(size_t)(m0 + r) * K + k0 + cs], As + off);
      async16(&B[(size_t)(n0 + r) * K + k0 + cs], Bs + off);
    }
    __syncthreads();
#pragma unroll
    for (int kk = 0; kk < 2; ++kk) {
      bf16x8 af[4], bfr[4];
#pragma unroll
      for (int mi = 0; mi < 4; ++mi)
        af[mi] = *reinterpret_cast<const bf16x8*>(&As[swz(wr * 64 + mi * 16 + lr, kk * 32 + lk)]);
#pragma unroll
      for (int ni = 0; ni < 4; ++ni)
        bfr[ni] = *reinterpret_cast<const bf16x8*>(&Bs[swz(wc * 64 + ni * 16 + lr, kk * 32 + lk)]);
#pragma unroll
      for (int mi = 0; mi < 4; ++mi)
#pragma unroll
        for (int ni = 0; ni < 4; ++ni)
          acc[mi][ni] = __builtin_amdgcn_mfma_f32_16x16x32_bf16(af[mi], bfr[ni], acc[mi][ni], 0, 0, 0);
    }
  }
  const int rg = (lane >> 4) * 4;
#pragma unroll
  for (int mi = 0; mi < 4; ++mi)
#pragma unroll
    for (int ni = 0; ni < 4; ++ni)
#pragma unroll
      for (int q = 0; q < 4; ++q) {
        int row = m0 + wr * 64 + mi * 16 + rg + q;
        int col = n0 + wc * 64 + ni * 16 + lr;
        store_val(&C[(size_t)row * ldc + col], acc[mi][ni][q]);
      }
}

// ---------------- fixed-shift flash attention, register-only P ----------------
// ALiBi fixed shift (slope2*q+12) removes all max tracking.  Swapped QK^T
// (mfma(kf,qf) -> S^T) leaves lane (lg, q=l&15) holding P[q][ni*16+lg*4+r];
// cvt_pk + permlane32_swap + ds_swizzle(xor16) + cndmask rebuilds the PV
// A-operand fragments P[q][kk*32+lg*8+j] entirely in registers -- no P LDS.
// Row-sums (denominators) via ones-MFMA land in the oacc row layout.
__global__ __launch_bounds__(256) void k_attn5(
    const u16* __restrict__ Y, const u16* __restrict__ Vt, u16* __restrict__ Og) {
  __shared__ __align__(16) u16 Ks[2][4096];
  __shared__ __align__(16) u16 Vs[2][4096];

  const int tid = threadIdx.x;
  const int lane = tid & 63;
  const int wave = tid >> 6;
  const int lr = lane & 15;
  const int lg = lane >> 4;
  const int lk = lg * 8;
  const bool odd = (lane & 16) != 0;

  const int orig = blockIdx.x;
  const int wg = (orig & 7) * 64 + (orig >> 3);   // XCD-chunked remap (512%8==0)
  const int bh = wg >> 4;                          // 0..31
  const int pr = wg & 15;                          // 0..15
  const int b = bh >> 4, h = bh & 15;
  const int tlo = pr, thi = 31 - pr;

  const float LOG2E = 1.4426950408889634f;
  const float slope2 = exp2f(-0.5f * (float)(h + 1)) * LOG2E;

  const u16* Kb = Y + (size_t)b * T_DIM * Y_LD + 1024 + h * DH;
  const u16* Vb = Vt + (size_t)bh * DH * T_DIM;

  const int tqarr[2] = {tlo, thi};
  // Q fragments (pre-scaled by 1/sqrt(dh)*log2e); MFMA B-operand.
  bf16x8 qf[2][2];
#pragma unroll
  for (int t = 0; t < 2; ++t) {
    const int qrow = tqarr[t] * 64 + wave * 16 + lr;
#pragma unroll
    for (int kk = 0; kk < 2; ++kk)
      qf[t][kk] = *reinterpret_cast<const bf16x8*>(
          &Y[(size_t)(b * T_DIM + qrow) * Y_LD + h * DH + kk * 32 + lk]);
  }

  // per-lane additive constants: nkb[ni*4+r] = -slope2*k_local - 12
  float nkb[16];
#pragma unroll
  for (int ni = 0; ni < 4; ++ni)
#pragma unroll
    for (int r = 0; r < 4; ++r)
      nkb[ni * 4 + r] = -slope2 * (float)(ni * 16 + lg * 4 + r) - 12.0f;

  bf16x8 ones;
#pragma unroll
  for (int j = 0; j < 8; ++j) ones[j] = (bf16_t)1.0f;

  f32x4 oacc[2][4] = {};
  f32x4 lacc[2] = {};

  auto stage = [&](int bufi, int kt) {
    const int kv0 = kt * 64;
#pragma unroll
    for (int q = 0; q < 2; ++q) {
      const int off = (q * 4 + wave) * 512;
      const int e = off + lane * 8;
      const int r = e >> 6, c = e & 63;
      const int cs = c ^ ((r & 7) << 3);
      async16(Kb + (size_t)(kv0 + r) * Y_LD + cs, &Ks[bufi][off]);
      async16(Vb + (size_t)r * T_DIM + kv0 + cs, &Vs[bufi][off]);
    }
  };

  stage(0, 0);
  __syncthreads();
  int buf = 0;

  for (int kt = 0; kt <= thi; ++kt) {
    if (kt < thi) stage(buf ^ 1, kt + 1);
    const bool dolo = (kt <= tlo);
    // S^T = K Q^T : lane holds k = kv0+ni*16+lg*4+r (reg r), q = q0w+lr (col)
    f32x4 sh[4] = {}, sl[4] = {};
#pragma unroll
    for (int kk = 0; kk < 2; ++kk)
#pragma unroll
      for (int ni = 0; ni < 4; ++ni) {
        bf16x8 kf = *reinterpret_cast<const bf16x8*>(&Ks[buf][swz(ni * 16 + lr, kk * 32 + lk)]);
        sh[ni] = __builtin_amdgcn_mfma_f32_16x16x32_bf16(kf, qf[1][kk], sh[ni], 0, 0, 0);
        if (dolo) sl[ni] = __builtin_amdgcn_mfma_f32_16x16x32_bf16(kf, qf[0][kk], sl[ni], 0, 0, 0);
      }
    const float ck = -slope2 * (float)(kt * 64);
    // softmax (fixed shift) + pack + in-register fragment build
    uint4 PW[2][2];
#pragma unroll
    for (int t = 0; t < 2; ++t) {
      if (t == 0 && !dolo) continue;
      const f32x4* sa = (t == 0) ? sl : sh;
      const bool diag = (kt == tqarr[t]);
      u32 pk[4][2];
#pragma unroll
      for (int ni = 0; ni < 4; ++ni) {
        float p[4];
#pragma unroll
        for (int r = 0; r < 4; ++r) {
          float s = sa[ni][r] + nkb[ni * 4 + r] + ck;
          if (diag && (ni * 16 + lg * 4 + r) > (wave * 16 + lr)) s = -INFINITY;
          p[r] = fexp2(s);
        }
        pk[ni][0] = pack2(p[0], p[1]);
        pk[ni][1] = pack2(p[2], p[3]);
      }
#pragma unroll
      for (int kk = 0; kk < 2; ++kk) {
        redist_pair(pk[2 * kk][0], pk[2 * kk + 1][0], odd, PW[t][kk].x, PW[t][kk].z);
        redist_pair(pk[2 * kk][1], pk[2 * kk + 1][1], odd, PW[t][kk].y, PW[t][kk].w);
      }
    }
    // O += P @ V ; denominators via ones-MFMA
#pragma unroll
    for (int kk = 0; kk < 2; ++kk) {
      bf16x8 ph = __builtin_bit_cast(bf16x8, PW[1][kk]);
      bf16x8 pl = ph;
      if (dolo) pl = __builtin_bit_cast(bf16x8, PW[0][kk]);
      lacc[1] = __builtin_amdgcn_mfma_f32_16x16x32_bf16(ph, ones, lacc[1], 0, 0, 0);
      if (dolo) lacc[0] = __builtin_amdgcn_mfma_f32_16x16x32_bf16(pl, ones, lacc[0], 0, 0, 0);
#pragma unroll
      for (int f = 0; f < 4; ++f) {
        bf16x8 vf = *reinterpret_cast<const bf16x8*>(&Vs[buf][swz(f * 16 + lr, kk * 32 + lk)]);
        oacc[1][f] = __builtin_amdgcn_mfma_f32_16x16x32_bf16(ph, vf, oacc[1][f], 0, 0, 0);
        if (dolo) oacc[0][f] = __builtin_amdgcn_mfma_f32_16x16x32_bf16(pl, vf, oacc[0][f], 0, 0, 0);
      }
    }
    __syncthreads();
    buf ^= 1;
  }

  // normalize + store (lacc rows align with oacc rows: q = q0w + lg*4 + r)
#pragma unroll
  for (int t = 0; t < 2; ++t) {
    float linv[4];
#pragma unroll
    for (int r = 0; r < 4; ++r) linv[r] = 1.0f / lacc[t][r];
#pragma unroll
    for (int f = 0; f < 4; ++f)
#pragma unroll
      for (int r = 0; r < 4; ++r) {
        int q = tqarr[t] * 64 + wave * 16 + lg * 4 + r;
        Og[(size_t)(b * T_DIM + q) * E_DIM + h * DH + f * 16 + lr] =
            f2bf(oacc[t][f][r] * linv[r]);
      }
  }
}

extern "C" void kernel_launch(void* const* d_in, const int* in_sizes, int n_in,
                              void* d_out, int out_size, void* d_ws, size_t ws_size,
                              hipStream_t stream) {
  const float* x  = (const float*)d_in[0];
  const float* Wq = (const float*)d_in[1];
  const float* Aq = (const float*)d_in[2];
  const float* Bq = (const float*)d_in[3];
  const float* Wk = (const float*)d_in[4];
  const float* Ak = (const float*)d_in[5];
  const float* Bk = (const float*)d_in[6];
  const float* Wv = (const float*)d_in[7];
  const float* Av = (const float*)d_in[8];
  const float* Bv = (const float*)d_in[9];
  const float* Wp = (const float*)d_in[10];
  float* out = (float*)d_out;

  char* ws = (char*)d_ws;
  u16* xb   = (u16*)(ws);                        // 4096x1024 bf16  (8 MB)
  u16* VtB  = (u16*)(ws);                        // reuses xb region after QKV GEMM
  u16* Weff = (u16*)(ws + 8388608);              // 3x1024x1024 bf16 (6 MB)
  u16* Wpb  = (u16*)(ws + 14680064);             // 1024x1024 bf16  (2 MB)
  u16* Yq   = (u16*)(ws + 16777216);             // 4096x3072 bf16  (24 MB)
  u16* Og   = (u16*)(ws + 41943040);             // 4096x1024 bf16  (8 MB)

  const float ISQ2 = 0.125f * 1.4426950408889634f;  // 1/sqrt(dh) * log2(e)

  k_cast_bf16<<<4096, 256, 0, stream>>>(x, xb, BT * E_DIM);
  k_weff3<<<12288, 256, 0, stream>>>(Wq, Aq, Bq, Wk, Ak, Bk, Wv, Av, Bv, Weff, ISQ2);
  k_cast_bf16<<<1024, 256, 0, stream>>>(Wp, Wpb, E_DIM * E_DIM);
  {
    dim3 grid(Y_LD / 128, BT / 128);
    k_gemm_bt<u16><<<grid, 256, 0, stream>>>(xb, Weff, Yq, E_DIM, Y_LD);
  }
  {
    dim3 grid(T_DIM / 64, 2 * H_NUM);
    k_vtrans<<<grid, 256, 0, stream>>>(Yq, VtB);
  }
  k_attn5<<<512, 256, 0, stream>>>(Yq, VtB, Og);
  {
    dim3 grid(E_DIM / 128, BT / 128);
    k_gemm_bt<float><<<grid, 256, 0, stream>>>(Og, Wpb, out, E_DIM, E_DIM);
  }
}

// Round 6
// 117.200 us; speedup vs baseline: 2.6540x; 1.1628x over previous
//
#include <hip/hip_runtime.h>

typedef unsigned short u16;
typedef unsigned int   u32;
typedef __bf16 bf16_t;
typedef bf16_t bf16x8 __attribute__((ext_vector_type(8)));
typedef bf16_t bf16x2v __attribute__((ext_vector_type(2)));
typedef float  f32x4  __attribute__((ext_vector_type(4)));

#define E_DIM 1024
#define T_DIM 2048
#define H_NUM 16
#define DH 64
#define BT 4096          // B*T
#define Y_LD 2048        // Q|K fused row stride (V goes to Vt directly)

__device__ __forceinline__ u16 f2bf(float f) {
  u32 u = __builtin_bit_cast(u32, f);
  u32 r = (u + 0x7fffu + ((u >> 16) & 1u)) >> 16;
  return (u16)r;
}

__device__ __forceinline__ float fexp2(float x) {
#if __has_builtin(__builtin_amdgcn_exp2f)
  return __builtin_amdgcn_exp2f(x);
#else
  return exp2f(x);
#endif
}

// XOR swizzle for [R][64]-element bf16 LDS tiles (row = 128B).
__device__ __forceinline__ int swz(int r, int c) {
  return r * 64 + (c ^ ((r & 7) << 3));
}

__device__ __forceinline__ void store_val(float* p, float v) { *p = v; }
__device__ __forceinline__ void store_val(u16* p, float v)   { *p = f2bf(v); }

typedef __attribute__((address_space(3))) unsigned int as3_u32;
typedef const __attribute__((address_space(1))) unsigned int as1_u32;

__device__ __forceinline__ void async16(const u16* g, u16* l) {
  __builtin_amdgcn_global_load_lds((as1_u32*)g, (as3_u32*)l, 16, 0, 0);
}

// pack two f32 -> one u32 of 2 bf16 (v_cvt_pk_bf16_f32)
__device__ __forceinline__ u32 pack2(float a, float b) {
  bf16x2v v;
  v[0] = (bf16_t)a;
  v[1] = (bf16_t)b;
  return __builtin_bit_cast(u32, v);
}

// v_permlane32_swap_b32: a<-[Alo|Blo], b<-[Ahi|Bhi]
__device__ __forceinline__ void plswap(u32& a, u32& b) {
#if __has_builtin(__builtin_amdgcn_permlane32_swap)
  typedef u32 u32x2 __attribute__((ext_vector_type(2)));
  u32x2 r = __builtin_amdgcn_permlane32_swap(a, b, false, false);
  a = r[0];
  b = r[1];
#else
  asm volatile("v_permlane32_swap_b32 %0, %1" : "+v"(a), "+v"(b));
#endif
}

// Redistribute one (A,B) bf16x2 pair into PV A-operand fragment words.
__device__ __forceinline__ void redist_pair(u32 A, u32 B, bool odd, u32& wj, u32& wj2) {
  plswap(A, B);
  u32 sA = __builtin_amdgcn_ds_swizzle(A, 0x401F);  // lane ^ 16
  u32 sB = __builtin_amdgcn_ds_swizzle(B, 0x401F);
  wj  = odd ? sB : A;
  wj2 = odd ? B : sA;
}

// ---------------- fused prep: x-cast | 3x LoRA-fold | Wp-cast ----------------
__global__ __launch_bounds__(256) void k_prep(
    const float* __restrict__ x,
    const float* __restrict__ W0, const float* __restrict__ A0, const float* __restrict__ B0,
    const float* __restrict__ W1, const float* __restrict__ A1, const float* __restrict__ B1,
    const float* __restrict__ W2, const float* __restrict__ A2, const float* __restrict__ B2,
    const float* __restrict__ Wp,
    u16* __restrict__ xb, u16* __restrict__ Weff, u16* __restrict__ Wpb, float s0) {
  const int blk = blockIdx.x;
  const int tid = threadIdx.x;
  if (blk < 4096) {                        // x cast: 4M elements
    int i = (blk * 256 + tid) * 4;
    float4 v = *reinterpret_cast<const float4*>(x + i);
    u32 lo = (u32)f2bf(v.x) | ((u32)f2bf(v.y) << 16);
    u32 hi = (u32)f2bf(v.z) | ((u32)f2bf(v.w) << 16);
    *reinterpret_cast<uint2*>(xb + i) = make_uint2(lo, hi);
  } else if (blk < 7168) {                 // LoRA fold: 3x 1M elements (vec4)
    int e4 = (blk - 4096) * 256 + tid;     // [0, 786432)
    int m = e4 >> 18;                      // 262144 vec4 per matrix
    int e = (e4 & 262143) * 4;
    const float* W  = (m == 0) ? W0 : (m == 1) ? W1 : W2;
    const float* A  = (m == 0) ? A0 : (m == 1) ? A1 : A2;
    const float* Bm = (m == 0) ? B0 : (m == 1) ? B1 : B2;
    const float sc  = (m == 0) ? s0 : 1.0f;
    int o = e >> 10, i = e & 1023;
    float4 wv = *reinterpret_cast<const float4*>(W + e);
    float acc[4] = {wv.x, wv.y, wv.z, wv.w};
#pragma unroll
    for (int r = 0; r < 8; ++r) {
      float a2 = 2.0f * A[o * 8 + r];
      float4 bv = *reinterpret_cast<const float4*>(Bm + r * 1024 + i);
      acc[0] += a2 * bv.x; acc[1] += a2 * bv.y; acc[2] += a2 * bv.z; acc[3] += a2 * bv.w;
    }
    u32 lo = (u32)f2bf(acc[0] * sc) | ((u32)f2bf(acc[1] * sc) << 16);
    u32 hi = (u32)f2bf(acc[2] * sc) | ((u32)f2bf(acc[3] * sc) << 16);
    *reinterpret_cast<uint2*>(Weff + (size_t)m * 1048576 + e) = make_uint2(lo, hi);
  } else {                                 // Wp cast: 1M elements
    int i = ((blk - 7168) * 256 + tid) * 4;
    float4 v = *reinterpret_cast<const float4*>(Wp + i);
    u32 lo = (u32)f2bf(v.x) | ((u32)f2bf(v.y) << 16);
    u32 hi = (u32)f2bf(v.z) | ((u32)f2bf(v.w) << 16);
    *reinterpret_cast<uint2*>(Wpb + i) = make_uint2(lo, hi);
  }
}

// ---------------- GEMM: C[m][n] = sum_k A[m][k]*B[n][k] ----------------
// QKV mode: blocks with n0>=2048 compute the V projection TRANSPOSED
// (operand-swapped MFMA) and write straight to Vt[b][h][d][t].
template <typename OUT_T, bool QKV>
__global__ __launch_bounds__(256) void k_gemm_bt(
    const u16* __restrict__ A, const u16* __restrict__ B,
    OUT_T* __restrict__ C, u16* __restrict__ Vt, int K, int ldc) {
  __shared__ __align__(16) u16 As[128 * 64];
  __shared__ __align__(16) u16 Bs[128 * 64];
  const int tid  = threadIdx.x;
  const int lane = tid & 63;
  const int wave = tid >> 6;
  const int wr = wave >> 1, wc = wave & 1;
  const int m0 = blockIdx.y * 128;
  const int n0 = blockIdx.x * 128;
  const int lr = lane & 15;
  const int lk = (lane >> 4) * 8;
  const bool vmode = QKV && (n0 >= 2048);

  f32x4 acc[4][4] = {};

  for (int k0 = 0; k0 < K; k0 += 64) {
    __syncthreads();
#pragma unroll
    for (int p = 0; p < 4; ++p) {
      const int off = (p * 4 + wave) * 512;
      const int e = off + lane * 8;
      const int r = e >> 6, c = e & 63;
      const int cs = c ^ ((r & 7) << 3);
      async16(&A[(size_t)(m0 + r) * K + k0 + cs], As + off);
      async16(&B[(size_t)(n0 + r) * K + k0 + cs], Bs + off);
    }
    __syncthreads();
#pragma unroll
    for (int kk = 0; kk < 2; ++kk) {
      bf16x8 af[4], bfr[4];
#pragma unroll
      for (int mi = 0; mi < 4; ++mi)
        af[mi] = *reinterpret_cast<const bf16x8*>(&As[swz(wr * 64 + mi * 16 + lr, kk * 32 + lk)]);
#pragma unroll
      for (int ni = 0; ni < 4; ++ni)
        bfr[ni] = *reinterpret_cast<const bf16x8*>(&Bs[swz(wc * 64 + ni * 16 + lr, kk * 32 + lk)]);
      if (vmode) {
#pragma unroll
        for (int mi = 0; mi < 4; ++mi)
#pragma unroll
          for (int ni = 0; ni < 4; ++ni)
            acc[mi][ni] = __builtin_amdgcn_mfma_f32_16x16x32_bf16(bfr[ni], af[mi], acc[mi][ni], 0, 0, 0);
      } else {
#pragma unroll
        for (int mi = 0; mi < 4; ++mi)
#pragma unroll
          for (int ni = 0; ni < 4; ++ni)
            acc[mi][ni] = __builtin_amdgcn_mfma_f32_16x16x32_bf16(af[mi], bfr[ni], acc[mi][ni], 0, 0, 0);
      }
    }
  }
  const int rg = (lane >> 4) * 4;
  if (vmode) {
    // acc rows = weight-out (o), cols = token (t); coalesced along t.
#pragma unroll
    for (int mi = 0; mi < 4; ++mi)
#pragma unroll
      for (int ni = 0; ni < 4; ++ni)
#pragma unroll
        for (int q = 0; q < 4; ++q) {
          int o = n0 - 2048 + wc * 64 + ni * 16 + rg + q;
          int h = o >> 6, d = o & 63;
          int rowm = m0 + wr * 64 + mi * 16 + lr;
          int b = rowm >> 11, t = rowm & 2047;
          Vt[(size_t)(((b << 4) + h) * 64 + d) * 2048 + t] = f2bf(acc[mi][ni][q]);
        }
  } else {
#pragma unroll
    for (int mi = 0; mi < 4; ++mi)
#pragma unroll
      for (int ni = 0; ni < 4; ++ni)
#pragma unroll
        for (int q = 0; q < 4; ++q) {
          int row = m0 + wr * 64 + mi * 16 + rg + q;
          int col = n0 + wc * 64 + ni * 16 + lr;
          store_val(&C[(size_t)row * ldc + col], acc[mi][ni][q]);
        }
  }
}

// ---------------- fixed-shift flash attention, 1 q-tile/block ----------------
// 1024 blocks; balanced qt permutation keeps per-CU work constant under
// round-robin dispatch.  Diagonal tile peeled.  Register-only P (cvt_pk +
// permlane32_swap + ds_swizzle).  Denominators via ones-MFMA.
__global__ __launch_bounds__(256) void k_attn6(
    const u16* __restrict__ Y, const u16* __restrict__ Vt, u16* __restrict__ Og) {
  __shared__ __align__(16) u16 Ks[2][4096];
  __shared__ __align__(16) u16 Vs[2][4096];

  const int tid = threadIdx.x;
  const int lane = tid & 63;
  const int wave = tid >> 6;
  const int lr = lane & 15;
  const int lg = lane >> 4;
  const int lk = lg * 8;
  const bool odd = (lane & 16) != 0;

  const int orig = blockIdx.x;
  const int bh = orig & 31;
  const int hi = orig >> 5;                        // 0..31
  const int j = hi >> 3, hh = hi & 7;
  const int qt = 31 - (j * 8 + ((j & 1) ? (7 - hh) : hh));  // balanced + big-first
  const int b = bh >> 4, h = bh & 15;

  const float LOG2E = 1.4426950408889634f;
  const float slope2 = exp2f(-0.5f * (float)(h + 1)) * LOG2E;

  const u16* Kb = Y + (size_t)b * T_DIM * Y_LD + 1024 + h * DH;
  const u16* Vb = Vt + (size_t)bh * DH * T_DIM;

  // Q fragments (pre-scaled by 1/sqrt(dh)*log2e); MFMA B-operand.
  bf16x8 qf[2];
  {
    const int qrow = qt * 64 + wave * 16 + lr;
#pragma unroll
    for (int kk = 0; kk < 2; ++kk)
      qf[kk] = *reinterpret_cast<const bf16x8*>(
          &Y[(size_t)(b * T_DIM + qrow) * Y_LD + h * DH + kk * 32 + lk]);
  }

  // per-lane additive constants: nkb[ni*4+r] = -slope2*k_local - 12
  float nkb[16];
#pragma unroll
  for (int ni = 0; ni < 4; ++ni)
#pragma unroll
    for (int r = 0; r < 4; ++r)
      nkb[ni * 4 + r] = -slope2 * (float)(ni * 16 + lg * 4 + r) - 12.0f;

  bf16x8 ones;
#pragma unroll
  for (int jj = 0; jj < 8; ++jj) ones[jj] = (bf16_t)1.0f;

  f32x4 oacc[4] = {};
  f32x4 lacc = {};

  auto stage = [&](int bufi, int kt) {
    const int kv0 = kt * 64;
#pragma unroll
    for (int q = 0; q < 2; ++q) {
      const int off = (q * 4 + wave) * 512;
      const int e = off + lane * 8;
      const int r = e >> 6, c = e & 63;
      const int cs = c ^ ((r & 7) << 3);
      async16(Kb + (size_t)(kv0 + r) * Y_LD + cs, &Ks[bufi][off]);
      async16(Vb + (size_t)r * T_DIM + kv0 + cs, &Vs[bufi][off]);
    }
  };

  stage(0, 0);
  __syncthreads();
  int buf = 0;

  auto step = [&](int kt, bool DIAG, bool PREF) {
    if (PREF) stage(buf ^ 1, kt + 1);
    // S^T = K Q^T : lane holds k = kv0+ni*16+lg*4+r (reg r), q = q0w+lr (col)
    f32x4 s[4] = {};
#pragma unroll
    for (int kk = 0; kk < 2; ++kk)
#pragma unroll
      for (int ni = 0; ni < 4; ++ni) {
        bf16x8 kf = *reinterpret_cast<const bf16x8*>(&Ks[buf][swz(ni * 16 + lr, kk * 32 + lk)]);
        s[ni] = __builtin_amdgcn_mfma_f32_16x16x32_bf16(kf, qf[kk], s[ni], 0, 0, 0);
      }
    const float ck = -slope2 * (float)(kt * 64);
    u32 pk[4][2];
#pragma unroll
    for (int ni = 0; ni < 4; ++ni) {
      float p[4];
#pragma unroll
      for (int r = 0; r < 4; ++r) {
        float sc = s[ni][r] + nkb[ni * 4 + r] + ck;
        if (DIAG && (ni * 16 + lg * 4 + r) > (wave * 16 + lr)) sc = -INFINITY;
        p[r] = fexp2(sc);
      }
      pk[ni][0] = pack2(p[0], p[1]);
      pk[ni][1] = pack2(p[2], p[3]);
    }
    uint4 PW[2];
#pragma unroll
    for (int kk = 0; kk < 2; ++kk) {
      redist_pair(pk[2 * kk][0], pk[2 * kk + 1][0], odd, PW[kk].x, PW[kk].z);
      redist_pair(pk[2 * kk][1], pk[2 * kk + 1][1], odd, PW[kk].y, PW[kk].w);
    }
#pragma unroll
    for (int kk = 0; kk < 2; ++kk) {
      bf16x8 ph = __builtin_bit_cast(bf16x8, PW[kk]);
      lacc = __builtin_amdgcn_mfma_f32_16x16x32_bf16(ph, ones, lacc, 0, 0, 0);
#pragma unroll
      for (int f = 0; f < 4; ++f) {
        bf16x8 vf = *reinterpret_cast<const bf16x8*>(&Vs[buf][swz(f * 16 + lr, kk * 32 + lk)]);
        oacc[f] = __builtin_amdgcn_mfma_f32_16x16x32_bf16(ph, vf, oacc[f], 0, 0, 0);
      }
    }
    __syncthreads();
    buf ^= 1;
  };

  for (int kt = 0; kt < qt; ++kt) step(kt, false, true);
  step(qt, true, false);

  // normalize + store
  float linv[4];
#pragma unroll
  for (int r = 0; r < 4; ++r) linv[r] = 1.0f / lacc[r];
#pragma unroll
  for (int f = 0; f < 4; ++f)
#pragma unroll
    for (int r = 0; r < 4; ++r) {
      int q = qt * 64 + wave * 16 + lg * 4 + r;
      Og[(size_t)(b * T_DIM + q) * E_DIM + h * DH + f * 16 + lr] =
          f2bf(oacc[f][r] * linv[r]);
    }
}

extern "C" void kernel_launch(void* const* d_in, const int* in_sizes, int n_in,
                              void* d_out, int out_size, void* d_ws, size_t ws_size,
                              hipStream_t stream) {
  const float* x  = (const float*)d_in[0];
  const float* Wq = (const float*)d_in[1];
  const float* Aq = (const float*)d_in[2];
  const float* Bq = (const float*)d_in[3];
  const float* Wk = (const float*)d_in[4];
  const float* Ak = (const float*)d_in[5];
  const float* Bk = (const float*)d_in[6];
  const float* Wv = (const float*)d_in[7];
  const float* Av = (const float*)d_in[8];
  const float* Bv = (const float*)d_in[9];
  const float* Wp = (const float*)d_in[10];
  float* out = (float*)d_out;

  char* ws = (char*)d_ws;
  u16* xb   = (u16*)(ws);                        // 4096x1024 bf16   0..8 MB (dead after QKV)
  u16* Og   = (u16*)(ws);                        // reuses xb after attn
  u16* Weff = (u16*)(ws + 8388608);              // 3x1024x1024 bf16 8..14 MB
  u16* Wpb  = (u16*)(ws + 14680064);             // 1024x1024 bf16   14..16 MB
  u16* Yq   = (u16*)(ws + 16777216);             // 4096x2048 bf16   16..32 MB (Q|K)
  u16* VtB  = (u16*)(ws + 33554432);             // 32x64x2048 bf16  32..40 MB (V^T)

  const float ISQ2 = 0.125f * 1.4426950408889634f;  // 1/sqrt(dh) * log2(e)

  // 1) fused prep: x cast | LoRA folds | Wp cast
  k_prep<<<8192, 256, 0, stream>>>(x, Wq, Aq, Bq, Wk, Ak, Bk, Wv, Av, Bv, Wp,
                                   xb, Weff, Wpb, ISQ2);
  // 2) fused QKV GEMM: Q|K -> Yq, V -> VtB (transposed in-epilogue)
  {
    dim3 grid(24, 32);
    k_gemm_bt<u16, true><<<grid, 256, 0, stream>>>(xb, Weff, Yq, VtB, E_DIM, Y_LD);
  }
  // 3) attention
  k_attn6<<<1024, 256, 0, stream>>>(Yq, VtB, Og);
  // 4) output projection: out = Og @ Wp^T  (fp32 out)
  {
    dim3 grid(8, 32);
    k_gemm_bt<float, false><<<grid, 256, 0, stream>>>(Og, Wpb, out, nullptr, E_DIM, E_DIM);
  }
}

// Round 7
// 112.589 us; speedup vs baseline: 2.7627x; 1.0410x over previous
//
#include <hip/hip_runtime.h>

typedef unsigned short u16;
typedef unsigned int   u32;
typedef __bf16 bf16_t;
typedef bf16_t bf16x8 __attribute__((ext_vector_type(8)));
typedef bf16_t bf16x2v __attribute__((ext_vector_type(2)));
typedef float  f32x4  __attribute__((ext_vector_type(4)));

#define E_DIM 1024
#define T_DIM 2048
#define H_NUM 16
#define DH 64
#define BT 4096          // B*T
#define Y_LD 2048        // Q|K fused row stride (V goes to Vt directly)

__device__ __forceinline__ u16 f2bf(float f) {
  u32 u = __builtin_bit_cast(u32, f);
  u32 r = (u + 0x7fffu + ((u >> 16) & 1u)) >> 16;
  return (u16)r;
}

__device__ __forceinline__ float fexp2(float x) {
#if __has_builtin(__builtin_amdgcn_exp2f)
  return __builtin_amdgcn_exp2f(x);
#else
  return exp2f(x);
#endif
}

// XOR swizzle for [R][64]-element bf16 LDS tiles (row = 128B).
__device__ __forceinline__ int swz(int r, int c) {
  return r * 64 + (c ^ ((r & 7) << 3));
}

__device__ __forceinline__ void store_val(float* p, float v) { *p = v; }
__device__ __forceinline__ void store_val(u16* p, float v)   { *p = f2bf(v); }

typedef __attribute__((address_space(3))) unsigned int as3_u32;
typedef const __attribute__((address_space(1))) unsigned int as1_u32;

__device__ __forceinline__ void async16(const u16* g, u16* l) {
  __builtin_amdgcn_global_load_lds((as1_u32*)g, (as3_u32*)l, 16, 0, 0);
}

// counted-vmcnt barrier (T4): leave N loads in flight, sync waves.
template <int N>
__device__ __forceinline__ void waitvm_barrier() {
  if constexpr (N == 4) asm volatile("s_waitcnt vmcnt(4)" ::: "memory");
  else                  asm volatile("s_waitcnt vmcnt(0)" ::: "memory");
  __builtin_amdgcn_s_barrier();
  __builtin_amdgcn_sched_barrier(0);
}

// pack two f32 -> one u32 of 2 bf16 (v_cvt_pk_bf16_f32)
__device__ __forceinline__ u32 pack2(float a, float b) {
  bf16x2v v;
  v[0] = (bf16_t)a;
  v[1] = (bf16_t)b;
  return __builtin_bit_cast(u32, v);
}

// v_permlane32_swap_b32: a<-[Alo|Blo], b<-[Ahi|Bhi]
__device__ __forceinline__ void plswap(u32& a, u32& b) {
#if __has_builtin(__builtin_amdgcn_permlane32_swap)
  typedef u32 u32x2 __attribute__((ext_vector_type(2)));
  u32x2 r = __builtin_amdgcn_permlane32_swap(a, b, false, false);
  a = r[0];
  b = r[1];
#else
  asm volatile("v_permlane32_swap_b32 %0, %1" : "+v"(a), "+v"(b));
#endif
}

// Redistribute one (A,B) bf16x2 pair into PV A-operand fragment words.
__device__ __forceinline__ void redist_pair(u32 A, u32 B, bool odd, u32& wj, u32& wj2) {
  plswap(A, B);
  u32 sA = __builtin_amdgcn_ds_swizzle(A, 0x401F);  // lane ^ 16
  u32 sB = __builtin_amdgcn_ds_swizzle(B, 0x401F);
  wj  = odd ? sB : A;
  wj2 = odd ? B : sA;
}

// ---------------- fused prep: x-cast | 3x LoRA-fold | Wp-cast ----------------
__global__ __launch_bounds__(256) void k_prep(
    const float* __restrict__ x,
    const float* __restrict__ W0, const float* __restrict__ A0, const float* __restrict__ B0,
    const float* __restrict__ W1, const float* __restrict__ A1, const float* __restrict__ B1,
    const float* __restrict__ W2, const float* __restrict__ A2, const float* __restrict__ B2,
    const float* __restrict__ Wp,
    u16* __restrict__ xb, u16* __restrict__ Weff, u16* __restrict__ Wpb, float s0) {
  const int blk = blockIdx.x;
  const int tid = threadIdx.x;
  if (blk < 4096) {                        // x cast: 4M elements
    int i = (blk * 256 + tid) * 4;
    float4 v = *reinterpret_cast<const float4*>(x + i);
    u32 lo = (u32)f2bf(v.x) | ((u32)f2bf(v.y) << 16);
    u32 hi = (u32)f2bf(v.z) | ((u32)f2bf(v.w) << 16);
    *reinterpret_cast<uint2*>(xb + i) = make_uint2(lo, hi);
  } else if (blk < 7168) {                 // LoRA fold: 3x 1M elements (vec4)
    int e4 = (blk - 4096) * 256 + tid;     // [0, 786432)
    int m = e4 >> 18;                      // 262144 vec4 per matrix
    int e = (e4 & 262143) * 4;
    const float* W  = (m == 0) ? W0 : (m == 1) ? W1 : W2;
    const float* A  = (m == 0) ? A0 : (m == 1) ? A1 : A2;
    const float* Bm = (m == 0) ? B0 : (m == 1) ? B1 : B2;
    const float sc  = (m == 0) ? s0 : 1.0f;
    int o = e >> 10, i = e & 1023;
    float4 wv = *reinterpret_cast<const float4*>(W + e);
    float acc[4] = {wv.x, wv.y, wv.z, wv.w};
#pragma unroll
    for (int r = 0; r < 8; ++r) {
      float a2 = 2.0f * A[o * 8 + r];
      float4 bv = *reinterpret_cast<const float4*>(Bm + r * 1024 + i);
      acc[0] += a2 * bv.x; acc[1] += a2 * bv.y; acc[2] += a2 * bv.z; acc[3] += a2 * bv.w;
    }
    u32 lo = (u32)f2bf(acc[0] * sc) | ((u32)f2bf(acc[1] * sc) << 16);
    u32 hi = (u32)f2bf(acc[2] * sc) | ((u32)f2bf(acc[3] * sc) << 16);
    *reinterpret_cast<uint2*>(Weff + (size_t)m * 1048576 + e) = make_uint2(lo, hi);
  } else {                                 // Wp cast: 1M elements
    int i = ((blk - 7168) * 256 + tid) * 4;
    float4 v = *reinterpret_cast<const float4*>(Wp + i);
    u32 lo = (u32)f2bf(v.x) | ((u32)f2bf(v.y) << 16);
    u32 hi = (u32)f2bf(v.z) | ((u32)f2bf(v.w) << 16);
    *reinterpret_cast<uint2*>(Wpb + i) = make_uint2(lo, hi);
  }
}

// ---------------- GEMM: C[m][n] = sum_k A[m][k]*B[n][k] ----------------
// QKV mode: blocks with n0>=2048 compute the V projection TRANSPOSED
// (operand-swapped MFMA) and write straight to Vt[b][h][d][t].
template <typename OUT_T, bool QKV>
__global__ __launch_bounds__(256) void k_gemm_bt(
    const u16* __restrict__ A, const u16* __restrict__ B,
    OUT_T* __restrict__ C, u16* __restrict__ Vt, int K, int ldc) {
  __shared__ __align__(16) u16 As[128 * 64];
  __shared__ __align__(16) u16 Bs[128 * 64];
  const int tid  = threadIdx.x;
  const int lane = tid & 63;
  const int wave = tid >> 6;
  const int wr = wave >> 1, wc = wave & 1;
  const int m0 = blockIdx.y * 128;
  const int n0 = blockIdx.x * 128;
  const int lr = lane & 15;
  const int lk = (lane >> 4) * 8;
  const bool vmode = QKV && (n0 >= 2048);

  f32x4 acc[4][4] = {};

  for (int k0 = 0; k0 < K; k0 += 64) {
    __syncthreads();
#pragma unroll
    for (int p = 0; p < 4; ++p) {
      const int off = (p * 4 + wave) * 512;
      const int e = off + lane * 8;
      const int r = e >> 6, c = e & 63;
      const int cs = c ^ ((r & 7) << 3);
      async16(&A[(size_t)(m0 + r) * K + k0 + cs], As + off);
      async16(&B[(size_t)(n0 + r) * K + k0 + cs], Bs + off);
    }
    __syncthreads();
#pragma unroll
    for (int kk = 0; kk < 2; ++kk) {
      bf16x8 af[4], bfr[4];
#pragma unroll
      for (int mi = 0; mi < 4; ++mi)
        af[mi] = *reinterpret_cast<const bf16x8*>(&As[swz(wr * 64 + mi * 16 + lr, kk * 32 + lk)]);
#pragma unroll
      for (int ni = 0; ni < 4; ++ni)
        bfr[ni] = *reinterpret_cast<const bf16x8*>(&Bs[swz(wc * 64 + ni * 16 + lr, kk * 32 + lk)]);
      if (vmode) {
#pragma unroll
        for (int mi = 0; mi < 4; ++mi)
#pragma unroll
          for (int ni = 0; ni < 4; ++ni)
            acc[mi][ni] = __builtin_amdgcn_mfma_f32_16x16x32_bf16(bfr[ni], af[mi], acc[mi][ni], 0, 0, 0);
      } else {
#pragma unroll
        for (int mi = 0; mi < 4; ++mi)
#pragma unroll
          for (int ni = 0; ni < 4; ++ni)
            acc[mi][ni] = __builtin_amdgcn_mfma_f32_16x16x32_bf16(af[mi], bfr[ni], acc[mi][ni], 0, 0, 0);
      }
    }
  }
  const int rg = (lane >> 4) * 4;
  if (vmode) {
    // acc rows = weight-out (o), cols = token (t); coalesced along t.
#pragma unroll
    for (int mi = 0; mi < 4; ++mi)
#pragma unroll
      for (int ni = 0; ni < 4; ++ni)
#pragma unroll
        for (int q = 0; q < 4; ++q) {
          int o = n0 - 2048 + wc * 64 + ni * 16 + rg + q;
          int h = o >> 6, d = o & 63;
          int rowm = m0 + wr * 64 + mi * 16 + lr;
          int b = rowm >> 11, t = rowm & 2047;
          Vt[(size_t)(((b << 4) + h) * 64 + d) * 2048 + t] = f2bf(acc[mi][ni][q]);
        }
  } else {
#pragma unroll
    for (int mi = 0; mi < 4; ++mi)
#pragma unroll
      for (int ni = 0; ni < 4; ++ni)
#pragma unroll
        for (int q = 0; q < 4; ++q) {
          int row = m0 + wr * 64 + mi * 16 + rg + q;
          int col = n0 + wc * 64 + ni * 16 + lr;
          store_val(&C[(size_t)row * ldc + col], acc[mi][ni][q]);
        }
  }
}

// ---------------- fixed-shift flash attention, counted-vmcnt pipeline ----------------
// 1024 blocks, balanced qt permutation.  Triple-buffered K/V staged 2 tiles
// ahead via global_load_lds; barriers keep the newest stage's 4 loads in
// flight (s_waitcnt vmcnt(4) + raw s_barrier).  Register-only P; ones-MFMA
// denominators; setprio around MFMA clusters.
__global__ __launch_bounds__(256) void k_attn7(
    const u16* __restrict__ Y, const u16* __restrict__ Vt, u16* __restrict__ Og) {
  __shared__ __align__(16) u16 Ks[3][4096];
  __shared__ __align__(16) u16 Vs[3][4096];

  const int tid = threadIdx.x;
  const int lane = tid & 63;
  const int wave = tid >> 6;
  const int lr = lane & 15;
  const int lg = lane >> 4;
  const int lk = lg * 8;
  const bool odd = (lane & 16) != 0;

  const int orig = blockIdx.x;
  const int bh = orig & 31;
  const int hi = orig >> 5;                        // 0..31
  const int j = hi >> 3, hh = hi & 7;
  const int qt = 31 - (j * 8 + ((j & 1) ? (7 - hh) : hh));  // balanced + big-first
  const int b = bh >> 4, h = bh & 15;

  const float LOG2E = 1.4426950408889634f;
  const float slope2 = exp2f(-0.5f * (float)(h + 1)) * LOG2E;

  const u16* Kb = Y + (size_t)b * T_DIM * Y_LD + 1024 + h * DH;
  const u16* Vb = Vt + (size_t)bh * DH * T_DIM;

  // Q fragments (pre-scaled by 1/sqrt(dh)*log2e); MFMA B-operand.
  bf16x8 qf[2];
  {
    const int qrow = qt * 64 + wave * 16 + lr;
#pragma unroll
    for (int kk = 0; kk < 2; ++kk)
      qf[kk] = *reinterpret_cast<const bf16x8*>(
          &Y[(size_t)(b * T_DIM + qrow) * Y_LD + h * DH + kk * 32 + lk]);
  }

  // per-lane additive constants: nkb[ni*4+r] = -slope2*k_local - 12
  float nkb[16];
#pragma unroll
  for (int ni = 0; ni < 4; ++ni)
#pragma unroll
    for (int r = 0; r < 4; ++r)
      nkb[ni * 4 + r] = -slope2 * (float)(ni * 16 + lg * 4 + r) - 12.0f;

  bf16x8 ones;
#pragma unroll
  for (int jj = 0; jj < 8; ++jj) ones[jj] = (bf16_t)1.0f;

  f32x4 oacc[4] = {};
  f32x4 lacc = {};

  auto stage = [&](int bufi, int kt) {
    const int kv0 = kt * 64;
#pragma unroll
    for (int q = 0; q < 2; ++q) {
      const int off = (q * 4 + wave) * 512;
      const int e = off + lane * 8;
      const int r = e >> 6, c = e & 63;
      const int cs = c ^ ((r & 7) << 3);
      async16(Kb + (size_t)(kv0 + r) * Y_LD + cs, &Ks[bufi][off]);
      async16(Vb + (size_t)r * T_DIM + kv0 + cs, &Vs[bufi][off]);
    }
  };

  auto step = [&](int kt, int buf, bool DIAG) {
    // S^T = K Q^T : lane holds k = kv0+ni*16+lg*4+r (reg r), q = q0w+lr (col)
    f32x4 s[4] = {};
    __builtin_amdgcn_s_setprio(1);
#pragma unroll
    for (int kk = 0; kk < 2; ++kk)
#pragma unroll
      for (int ni = 0; ni < 4; ++ni) {
        bf16x8 kf = *reinterpret_cast<const bf16x8*>(&Ks[buf][swz(ni * 16 + lr, kk * 32 + lk)]);
        s[ni] = __builtin_amdgcn_mfma_f32_16x16x32_bf16(kf, qf[kk], s[ni], 0, 0, 0);
      }
    __builtin_amdgcn_s_setprio(0);
    const float ck = -slope2 * (float)(kt * 64);
    u32 pk[4][2];
#pragma unroll
    for (int ni = 0; ni < 4; ++ni) {
      float p[4];
#pragma unroll
      for (int r = 0; r < 4; ++r) {
        float sc = s[ni][r] + nkb[ni * 4 + r] + ck;
        if (DIAG && (ni * 16 + lg * 4 + r) > (wave * 16 + lr)) sc = -INFINITY;
        p[r] = fexp2(sc);
      }
      pk[ni][0] = pack2(p[0], p[1]);
      pk[ni][1] = pack2(p[2], p[3]);
    }
    uint4 PW[2];
#pragma unroll
    for (int kk = 0; kk < 2; ++kk) {
      redist_pair(pk[2 * kk][0], pk[2 * kk + 1][0], odd, PW[kk].x, PW[kk].z);
      redist_pair(pk[2 * kk][1], pk[2 * kk + 1][1], odd, PW[kk].y, PW[kk].w);
    }
    __builtin_amdgcn_s_setprio(1);
#pragma unroll
    for (int kk = 0; kk < 2; ++kk) {
      bf16x8 ph = __builtin_bit_cast(bf16x8, PW[kk]);
      lacc = __builtin_amdgcn_mfma_f32_16x16x32_bf16(ph, ones, lacc, 0, 0, 0);
#pragma unroll
      for (int f = 0; f < 4; ++f) {
        bf16x8 vf = *reinterpret_cast<const bf16x8*>(&Vs[buf][swz(f * 16 + lr, kk * 32 + lk)]);
        oacc[f] = __builtin_amdgcn_mfma_f32_16x16x32_bf16(ph, vf, oacc[f], 0, 0, 0);
      }
    }
    __builtin_amdgcn_s_setprio(0);
  };

  // prologue: stage tiles 0 and 1; keep stage(1) in flight across the barrier
  stage(0, 0);
  if (qt >= 1) {
    stage(1, 1);
    waitvm_barrier<4>();
  } else {
    waitvm_barrier<0>();
  }

  int b0 = 0, b1 = 1, b2 = 2;   // rotating buffer ids (kt, kt+1, kt+2)
  for (int kt = 0; kt < qt; ++kt) {
    const bool pf = (kt + 2 <= qt);
    if (pf) stage(b2, kt + 2);
    step(kt, b0, false);
    if (pf) waitvm_barrier<4>();   // stage(kt+1) done; stage(kt+2) in flight
    else    waitvm_barrier<0>();   // last prefetch (stage(qt)) fully landed
    int t = b0; b0 = b1; b1 = b2; b2 = t;
  }
  step(qt, b0, true);

  // normalize + store
  float linv[4];
#pragma unroll
  for (int r = 0; r < 4; ++r) linv[r] = 1.0f / lacc[r];
#pragma unroll
  for (int f = 0; f < 4; ++f)
#pragma unroll
    for (int r = 0; r < 4; ++r) {
      int q = qt * 64 + wave * 16 + lg * 4 + r;
      Og[(size_t)(b * T_DIM + q) * E_DIM + h * DH + f * 16 + lr] =
          f2bf(oacc[f][r] * linv[r]);
    }
}

extern "C" void kernel_launch(void* const* d_in, const int* in_sizes, int n_in,
                              void* d_out, int out_size, void* d_ws, size_t ws_size,
                              hipStream_t stream) {
  const float* x  = (const float*)d_in[0];
  const float* Wq = (const float*)d_in[1];
  const float* Aq = (const float*)d_in[2];
  const float* Bq = (const float*)d_in[3];
  const float* Wk = (const float*)d_in[4];
  const float* Ak = (const float*)d_in[5];
  const float* Bk = (const float*)d_in[6];
  const float* Wv = (const float*)d_in[7];
  const float* Av = (const float*)d_in[8];
  const float* Bv = (const float*)d_in[9];
  const float* Wp = (const float*)d_in[10];
  float* out = (float*)d_out;

  char* ws = (char*)d_ws;
  u16* xb   = (u16*)(ws);                        // 4096x1024 bf16   0..8 MB (dead after QKV)
  u16* Og   = (u16*)(ws);                        // reuses xb after attn
  u16* Weff = (u16*)(ws + 8388608);              // 3x1024x1024 bf16 8..14 MB
  u16* Wpb  = (u16*)(ws + 14680064);             // 1024x1024 bf16   14..16 MB
  u16* Yq   = (u16*)(ws + 16777216);             // 4096x2048 bf16   16..32 MB (Q|K)
  u16* VtB  = (u16*)(ws + 33554432);             // 32x64x2048 bf16  32..40 MB (V^T)

  const float ISQ2 = 0.125f * 1.4426950408889634f;  // 1/sqrt(dh) * log2(e)

  // 1) fused prep: x cast | LoRA folds | Wp cast
  k_prep<<<8192, 256, 0, stream>>>(x, Wq, Aq, Bq, Wk, Ak, Bk, Wv, Av, Bv, Wp,
                                   xb, Weff, Wpb, ISQ2);
  // 2) fused QKV GEMM: Q|K -> Yq, V -> VtB (transposed in-epilogue)
  {
    dim3 grid(24, 32);
    k_gemm_bt<u16, true><<<grid, 256, 0, stream>>>(xb, Weff, Yq, VtB, E_DIM, Y_LD);
  }
  // 3) attention
  k_attn7<<<1024, 256, 0, stream>>>(Yq, VtB, Og);
  // 4) output projection: out = Og @ Wp^T  (fp32 out)
  {
    dim3 grid(8, 32);
    k_gemm_bt<float, false><<<grid, 256, 0, stream>>>(Og, Wpb, out, nullptr, E_DIM, E_DIM);
  }
}